// Round 1
// baseline (2248.258 us; speedup 1.0000x reference)
//
#include <hip/hip_runtime.h>
#include <math.h>

#define DIMX 1024
#define D_STATE 16
#define D_INNER 2048
#define DT_RANK 64
#define B_SZ 2
#define L_SEQ 1024
#define NTOK (B_SZ * L_SEQ)
#define EPSR 1e-5f

// ---------------- RMSNorm: one block per row ----------------
__global__ void rmsnorm_kernel(const float* __restrict__ x, const float* __restrict__ w,
                               float* __restrict__ xn) {
    int row = blockIdx.x;
    const float* xr = x + (size_t)row * DIMX;
    float* outr = xn + (size_t)row * DIMX;
    int t = threadIdx.x;
    float v[4];
    float ss = 0.f;
#pragma unroll
    for (int i = 0; i < 4; ++i) { v[i] = xr[t + i * 256]; ss += v[i] * v[i]; }
#pragma unroll
    for (int off = 32; off > 0; off >>= 1) ss += __shfl_down(ss, off);
    __shared__ float red[4];
    if ((t & 63) == 0) red[t >> 6] = ss;
    __syncthreads();
    float tot = red[0] + red[1] + red[2] + red[3];
    float scale = rsqrtf(tot * (1.f / DIMX) + EPSR);
#pragma unroll
    for (int i = 0; i < 4; ++i) outr[t + i * 256] = v[i] * scale * w[t + i * 256];
}

// ---------------- Generic GEMM: C[M,N] = A[M,K] * B[N,K]^T ----------------
// EPI: 0 = none, 1 = softplus(acc + bias[n]), 2 = acc + res[m*ldc + n]
template <int EPI>
__global__ void gemm_tn(const float* __restrict__ A, const float* __restrict__ B,
                        float* __restrict__ C, int M, int N, int K,
                        int lda, int ldb, int ldc,
                        const float* __restrict__ bias, const float* __restrict__ res) {
    const int BM = 64, BN = 64, BK = 16;
    __shared__ float As[BK][BM + 1];
    __shared__ float Bs[BK][BN + 1];
    int m0 = blockIdx.y * BM;
    int n0 = blockIdx.x * BN;
    int tid = threadIdx.x;
    int tx = tid & 15, ty = tid >> 4;
    float acc[4][4] = {};
    for (int k0 = 0; k0 < K; k0 += BK) {
#pragma unroll
        for (int i = 0; i < 4; ++i) {
            int idx = tid + i * 256;
            int r = idx >> 4, c = idx & 15;
            As[c][r] = A[(size_t)(m0 + r) * lda + k0 + c];
        }
#pragma unroll
        for (int i = 0; i < 4; ++i) {
            int idx = tid + i * 256;
            int r = idx >> 4, c = idx & 15;
            int n = n0 + r;
            Bs[c][r] = (n < N) ? B[(size_t)n * ldb + k0 + c] : 0.f;
        }
        __syncthreads();
#pragma unroll
        for (int k = 0; k < BK; ++k) {
            float a[4], b[4];
#pragma unroll
            for (int i = 0; i < 4; ++i) a[i] = As[k][ty * 4 + i];
#pragma unroll
            for (int j = 0; j < 4; ++j) b[j] = Bs[k][tx * 4 + j];
#pragma unroll
            for (int i = 0; i < 4; ++i)
#pragma unroll
                for (int j = 0; j < 4; ++j)
                    acc[i][j] = fmaf(a[i], b[j], acc[i][j]);
        }
        __syncthreads();
    }
#pragma unroll
    for (int i = 0; i < 4; ++i) {
        int m = m0 + ty * 4 + i;
#pragma unroll
        for (int j = 0; j < 4; ++j) {
            int n = n0 + tx * 4 + j;
            if (n < N) {
                float v = acc[i][j];
                if (EPI == 1) {
                    v += bias[n];
                    v = fmaxf(v, 0.f) + log1pf(expf(-fabsf(v)));  // stable softplus
                } else if (EPI == 2) {
                    v += res[(size_t)m * ldc + n];
                }
                C[(size_t)m * ldc + n] = v;
            }
        }
    }
}

// ---------------- Depthwise causal conv (d_conv=4) + SiLU ----------------
__global__ void conv_silu_kernel(const float* __restrict__ xz, const float* __restrict__ cw,
                                 const float* __restrict__ cb, float* __restrict__ u) {
    int idx = blockIdx.x * blockDim.x + threadIdx.x;   // over B*L*D_INNER
    if (idx >= B_SZ * L_SEQ * D_INNER) return;
    int d = idx & (D_INNER - 1);
    int bl = idx >> 11;                 // b*L + l
    int l = bl & (L_SEQ - 1);
    float accv = cb[d];
#pragma unroll
    for (int j = 0; j < 4; ++j) {
        int lp = l - 3 + j;
        if (lp >= 0)
            accv = fmaf(cw[d * 4 + j], xz[(size_t)(bl - l + lp) * (2 * D_INNER) + d], accv);
    }
    u[idx] = accv / (1.f + expf(-accv));   // SiLU
}

// ---------------- Sequential selective scan ----------------
// delta buffer is overwritten in-place with ys.
__global__ void scan_kernel(const float* __restrict__ xdbl, float* __restrict__ delta,
                            const float* __restrict__ u, const float* __restrict__ A_log) {
    int b = blockIdx.x >> 3;
    int d = ((blockIdx.x & 7) << 8) + threadIdx.x;
    float A[D_STATE];
#pragma unroll
    for (int s = 0; s < D_STATE; ++s) A[s] = -expf(A_log[d * D_STATE + s]);
    float h[D_STATE] = {};
    __shared__ float Bs[D_STATE], Cs[D_STATE];
    for (int l = 0; l < L_SEQ; ++l) {
        size_t tok = (size_t)b * L_SEQ + l;
        if (threadIdx.x < 32) {
            float v = xdbl[tok * 96 + DT_RANK + threadIdx.x];
            if (threadIdx.x < 16) Bs[threadIdx.x] = v;
            else Cs[threadIdx.x - 16] = v;
        }
        __syncthreads();
        float dlt = delta[tok * D_INNER + d];
        float ut = u[tok * D_INNER + d];
        float du = dlt * ut;
        float y = 0.f;
#pragma unroll
        for (int s = 0; s < D_STATE; ++s) {
            h[s] = expf(dlt * A[s]) * h[s] + du * Bs[s];
            y = fmaf(h[s], Cs[s], y);
        }
        delta[tok * D_INNER + d] = y;
        __syncthreads();
    }
}

// ---------------- y = (ys + u*D) * silu(z), in-place over ys ----------------
__global__ void gate_kernel(float* __restrict__ y, const float* __restrict__ u,
                            const float* __restrict__ xz, const float* __restrict__ Dp) {
    int idx = blockIdx.x * blockDim.x + threadIdx.x;
    if (idx >= B_SZ * L_SEQ * D_INNER) return;
    int d = idx & (D_INNER - 1);
    int bl = idx >> 11;
    float z = xz[(size_t)bl * (2 * D_INNER) + D_INNER + d];
    float yy = fmaf(u[idx], Dp[d], y[idx]);
    y[idx] = yy * (z / (1.f + expf(-z)));
}

extern "C" void kernel_launch(void* const* d_in, const int* in_sizes, int n_in,
                              void* d_out, int out_size, void* d_ws, size_t ws_size,
                              hipStream_t stream) {
    const float* x         = (const float*)d_in[0];
    const float* norm_w    = (const float*)d_in[1];
    const float* in_proj_w = (const float*)d_in[2];
    const float* conv_w    = (const float*)d_in[3];
    const float* conv_b    = (const float*)d_in[4];
    const float* x_proj_w  = (const float*)d_in[5];
    const float* dt_proj_w = (const float*)d_in[6];
    const float* dt_proj_b = (const float*)d_in[7];
    const float* A_log     = (const float*)d_in[8];
    const float* D_param   = (const float*)d_in[9];
    const float* out_proj_w= (const float*)d_in[10];
    float* out = (float*)d_out;

    float* ws    = (float*)d_ws;
    float* xn    = ws;                       // 2,097,152
    float* xz    = xn + 2097152;             // 8,388,608
    float* u     = xz + 8388608;             // 4,194,304
    float* xdbl  = u + 4194304;              // 196,608
    float* delta = xdbl + 196608;            // 4,194,304  (becomes ys, then y)

    // 1. RMSNorm
    rmsnorm_kernel<<<NTOK, 256, 0, stream>>>(x, norm_w, xn);
    // 2. in_proj: xz[2048,4096] = xn[2048,1024] @ W[4096,1024]^T
    gemm_tn<0><<<dim3(64, 32), 256, 0, stream>>>(xn, in_proj_w, xz,
        NTOK, 2 * D_INNER, DIMX, DIMX, DIMX, 2 * D_INNER, nullptr, nullptr);
    // 3. causal depthwise conv + SiLU -> u
    conv_silu_kernel<<<(B_SZ * L_SEQ * D_INNER) / 256, 256, 0, stream>>>(xz, conv_w, conv_b, u);
    // 4. x_proj: xdbl[2048,96] = u[2048,2048] @ W[96,2048]^T
    gemm_tn<0><<<dim3(2, 32), 256, 0, stream>>>(u, x_proj_w, xdbl,
        NTOK, DT_RANK + 2 * D_STATE, D_INNER, D_INNER, D_INNER, DT_RANK + 2 * D_STATE,
        nullptr, nullptr);
    // 5. dt_proj + softplus: delta[2048,2048] = softplus(dt[2048,64] @ W[2048,64]^T + b)
    gemm_tn<1><<<dim3(32, 32), 256, 0, stream>>>(xdbl, dt_proj_w, delta,
        NTOK, D_INNER, DT_RANK, DT_RANK + 2 * D_STATE, DT_RANK, D_INNER,
        dt_proj_b, nullptr);
    // 6. selective scan (ys written over delta)
    scan_kernel<<<B_SZ * (D_INNER / 256), 256, 0, stream>>>(xdbl, delta, u, A_log);
    // 7. gating: y = (ys + u*D) * silu(z)
    gate_kernel<<<(B_SZ * L_SEQ * D_INNER) / 256, 256, 0, stream>>>(delta, u, xz, D_param);
    // 8. out_proj + residual: out[2048,1024] = y[2048,2048] @ W[1024,2048]^T + x
    gemm_tn<2><<<dim3(16, 32), 256, 0, stream>>>(delta, out_proj_w, out,
        NTOK, DIMX, D_INNER, D_INNER, D_INNER, DIMX, nullptr, x);
}

// Round 2
// 1352.395 us; speedup vs baseline: 1.6624x; 1.6624x over previous
//
#include <hip/hip_runtime.h>
#include <math.h>

#define DIMX 1024
#define D_STATE 16
#define D_INNER 2048
#define DT_RANK 64
#define B_SZ 2
#define L_SEQ 1024
#define NTOK (B_SZ * L_SEQ)
#define EPSR 1e-5f

// ---------------- RMSNorm: one block per row ----------------
__global__ void rmsnorm_kernel(const float* __restrict__ x, const float* __restrict__ w,
                               float* __restrict__ xn) {
    int row = blockIdx.x;
    const float* xr = x + (size_t)row * DIMX;
    float* outr = xn + (size_t)row * DIMX;
    int t = threadIdx.x;
    float v[4];
    float ss = 0.f;
#pragma unroll
    for (int i = 0; i < 4; ++i) { v[i] = xr[t + i * 256]; ss += v[i] * v[i]; }
#pragma unroll
    for (int off = 32; off > 0; off >>= 1) ss += __shfl_down(ss, off);
    __shared__ float red[4];
    if ((t & 63) == 0) red[t >> 6] = ss;
    __syncthreads();
    float tot = red[0] + red[1] + red[2] + red[3];
    float scale = rsqrtf(tot * (1.f / DIMX) + EPSR);
#pragma unroll
    for (int i = 0; i < 4; ++i) outr[t + i * 256] = v[i] * scale * w[t + i * 256];
}

// ---------------- Generic GEMM: C[M,N] = A[M,K] * B[N,K]^T ----------------
// EPI: 0 = none, 1 = softplus(acc + bias[n]), 2 = acc + res[m*ldc + n]
template <int EPI>
__global__ void gemm_tn(const float* __restrict__ A, const float* __restrict__ B,
                        float* __restrict__ C, int M, int N, int K,
                        int lda, int ldb, int ldc,
                        const float* __restrict__ bias, const float* __restrict__ res) {
    const int BM = 64, BN = 64, BK = 16;
    __shared__ float As[BK][BM + 1];
    __shared__ float Bs[BK][BN + 1];
    int m0 = blockIdx.y * BM;
    int n0 = blockIdx.x * BN;
    int tid = threadIdx.x;
    int tx = tid & 15, ty = tid >> 4;
    float acc[4][4] = {};
    for (int k0 = 0; k0 < K; k0 += BK) {
#pragma unroll
        for (int i = 0; i < 4; ++i) {
            int idx = tid + i * 256;
            int r = idx >> 4, c = idx & 15;
            As[c][r] = A[(size_t)(m0 + r) * lda + k0 + c];
        }
#pragma unroll
        for (int i = 0; i < 4; ++i) {
            int idx = tid + i * 256;
            int r = idx >> 4, c = idx & 15;
            int n = n0 + r;
            Bs[c][r] = (n < N) ? B[(size_t)n * ldb + k0 + c] : 0.f;
        }
        __syncthreads();
#pragma unroll
        for (int k = 0; k < BK; ++k) {
            float a[4], b[4];
#pragma unroll
            for (int i = 0; i < 4; ++i) a[i] = As[k][ty * 4 + i];
#pragma unroll
            for (int j = 0; j < 4; ++j) b[j] = Bs[k][tx * 4 + j];
#pragma unroll
            for (int i = 0; i < 4; ++i)
#pragma unroll
                for (int j = 0; j < 4; ++j)
                    acc[i][j] = fmaf(a[i], b[j], acc[i][j]);
        }
        __syncthreads();
    }
#pragma unroll
    for (int i = 0; i < 4; ++i) {
        int m = m0 + ty * 4 + i;
#pragma unroll
        for (int j = 0; j < 4; ++j) {
            int n = n0 + tx * 4 + j;
            if (n < N) {
                float v = acc[i][j];
                if (EPI == 1) {
                    v += bias[n];
                    v = fmaxf(v, 0.f) + log1pf(expf(-fabsf(v)));  // stable softplus
                } else if (EPI == 2) {
                    v += res[(size_t)m * ldc + n];
                }
                C[(size_t)m * ldc + n] = v;
            }
        }
    }
}

// ---------------- Depthwise causal conv (d_conv=4) + SiLU ----------------
__global__ void conv_silu_kernel(const float* __restrict__ xz, const float* __restrict__ cw,
                                 const float* __restrict__ cb, float* __restrict__ u) {
    int idx = blockIdx.x * blockDim.x + threadIdx.x;   // over B*L*D_INNER
    if (idx >= B_SZ * L_SEQ * D_INNER) return;
    int d = idx & (D_INNER - 1);
    int bl = idx >> 11;                 // b*L + l
    int l = bl & (L_SEQ - 1);
    float accv = cb[d];
#pragma unroll
    for (int j = 0; j < 4; ++j) {
        int lp = l - 3 + j;
        if (lp >= 0)
            accv = fmaf(cw[d * 4 + j], xz[(size_t)(bl - l + lp) * (2 * D_INNER) + d], accv);
    }
    u[idx] = accv / (1.f + expf(-accv));   // SiLU
}

// ---------------- Sequential selective scan, lane-per-(channel,state) ----------------
// 1 wave = 4 channels x 16 states. 1024 waves total, no LDS, no barriers.
// delta buffer is overwritten in-place with ys.
__global__ void scan_kernel(const float* __restrict__ xdbl, float* delta,
                            const float* __restrict__ u, const float* __restrict__ A_log) {
    const int lane = threadIdx.x & 63;
    const int s = lane & 15;                                  // state index
    const int wid = (blockIdx.x << 2) + (threadIdx.x >> 6);   // global wave 0..1023
    const int gchan = (wid << 2) + (lane >> 4);               // 0..4095
    const int b = gchan >> 11;
    const int d = gchan & (D_INNER - 1);
    const float A = -__expf(A_log[d * D_STATE + s]);
    float h = 0.f;
    const size_t tok0 = (size_t)b * L_SEQ;
    const float* dp = delta + tok0 * D_INNER + d;
    const float* up = u + tok0 * D_INNER + d;
    const float* xp = xdbl + tok0 * 96 + DT_RANK + s;
    float* yp = delta + tok0 * D_INNER + d;

    // depth-2 software pipeline on the (h-independent) loads
    float dlt0 = dp[0], ut0 = up[0], Bv0 = xp[0], Cv0 = xp[16];
    float dlt1 = dp[D_INNER], ut1 = up[D_INNER], Bv1 = xp[96], Cv1 = xp[96 + 16];
    dp += 2 * D_INNER; up += 2 * D_INNER; xp += 2 * 96;

    for (int l = 0; l < L_SEQ; ++l) {
        float dlt2 = 0.f, ut2 = 0.f, Bv2 = 0.f, Cv2 = 0.f;
        if (l + 2 < L_SEQ) {                      // wave-uniform branch
            dlt2 = dp[0]; ut2 = up[0]; Bv2 = xp[0]; Cv2 = xp[16];
        }
        h = __expf(dlt0 * A) * h + dlt0 * ut0 * Bv0;
        float y = h * Cv0;
        y += __shfl_xor(y, 1);
        y += __shfl_xor(y, 2);
        y += __shfl_xor(y, 4);
        y += __shfl_xor(y, 8);
        if (s == 0) yp[0] = y;
        yp += D_INNER;
        dlt0 = dlt1; ut0 = ut1; Bv0 = Bv1; Cv0 = Cv1;
        dlt1 = dlt2; ut1 = ut2; Bv1 = Bv2; Cv1 = Cv2;
        dp += D_INNER; up += D_INNER; xp += 96;
    }
}

// ---------------- y = (ys + u*D) * silu(z), in-place over ys ----------------
__global__ void gate_kernel(float* __restrict__ y, const float* __restrict__ u,
                            const float* __restrict__ xz, const float* __restrict__ Dp) {
    int idx = blockIdx.x * blockDim.x + threadIdx.x;
    if (idx >= B_SZ * L_SEQ * D_INNER) return;
    int d = idx & (D_INNER - 1);
    int bl = idx >> 11;
    float z = xz[(size_t)bl * (2 * D_INNER) + D_INNER + d];
    float yy = fmaf(u[idx], Dp[d], y[idx]);
    y[idx] = yy * (z / (1.f + expf(-z)));
}

extern "C" void kernel_launch(void* const* d_in, const int* in_sizes, int n_in,
                              void* d_out, int out_size, void* d_ws, size_t ws_size,
                              hipStream_t stream) {
    const float* x         = (const float*)d_in[0];
    const float* norm_w    = (const float*)d_in[1];
    const float* in_proj_w = (const float*)d_in[2];
    const float* conv_w    = (const float*)d_in[3];
    const float* conv_b    = (const float*)d_in[4];
    const float* x_proj_w  = (const float*)d_in[5];
    const float* dt_proj_w = (const float*)d_in[6];
    const float* dt_proj_b = (const float*)d_in[7];
    const float* A_log     = (const float*)d_in[8];
    const float* D_param   = (const float*)d_in[9];
    const float* out_proj_w= (const float*)d_in[10];
    float* out = (float*)d_out;

    float* ws    = (float*)d_ws;
    float* xn    = ws;                       // 2,097,152
    float* xz    = xn + 2097152;             // 8,388,608
    float* u     = xz + 8388608;             // 4,194,304
    float* xdbl  = u + 4194304;              // 196,608
    float* delta = xdbl + 196608;            // 4,194,304  (becomes ys, then y)

    // 1. RMSNorm
    rmsnorm_kernel<<<NTOK, 256, 0, stream>>>(x, norm_w, xn);
    // 2. in_proj: xz[2048,4096] = xn[2048,1024] @ W[4096,1024]^T
    gemm_tn<0><<<dim3(64, 32), 256, 0, stream>>>(xn, in_proj_w, xz,
        NTOK, 2 * D_INNER, DIMX, DIMX, DIMX, 2 * D_INNER, nullptr, nullptr);
    // 3. causal depthwise conv + SiLU -> u
    conv_silu_kernel<<<(B_SZ * L_SEQ * D_INNER) / 256, 256, 0, stream>>>(xz, conv_w, conv_b, u);
    // 4. x_proj: xdbl[2048,96] = u[2048,2048] @ W[96,2048]^T
    gemm_tn<0><<<dim3(2, 32), 256, 0, stream>>>(u, x_proj_w, xdbl,
        NTOK, DT_RANK + 2 * D_STATE, D_INNER, D_INNER, D_INNER, DT_RANK + 2 * D_STATE,
        nullptr, nullptr);
    // 5. dt_proj + softplus: delta[2048,2048] = softplus(dt[2048,64] @ W[2048,64]^T + b)
    gemm_tn<1><<<dim3(32, 32), 256, 0, stream>>>(xdbl, dt_proj_w, delta,
        NTOK, D_INNER, DT_RANK, DT_RANK + 2 * D_STATE, DT_RANK, D_INNER,
        dt_proj_b, nullptr);
    // 6. selective scan: lane-per-(channel,state), 1024 waves (ys over delta)
    scan_kernel<<<256, 256, 0, stream>>>(xdbl, delta, u, A_log);
    // 7. gating: y = (ys + u*D) * silu(z)
    gate_kernel<<<(B_SZ * L_SEQ * D_INNER) / 256, 256, 0, stream>>>(delta, u, xz, D_param);
    // 8. out_proj + residual: out[2048,1024] = y[2048,2048] @ W[1024,2048]^T + x
    gemm_tn<2><<<dim3(16, 32), 256, 0, stream>>>(delta, out_proj_w, out,
        NTOK, DIMX, D_INNER, D_INNER, D_INNER, DIMX, nullptr, x);
}

// Round 3
// 439.551 us; speedup vs baseline: 5.1149x; 3.0768x over previous
//
#include <hip/hip_runtime.h>
#include <math.h>

#define DIMX 1024
#define D_STATE 16
#define D_INNER 2048
#define DT_RANK 64
#define B_SZ 2
#define L_SEQ 1024
#define NTOK (B_SZ * L_SEQ)
#define EPSR 1e-5f

typedef __attribute__((ext_vector_type(8))) short bf16x8;
typedef __attribute__((ext_vector_type(4))) int   i32x4;
typedef __attribute__((ext_vector_type(4))) float f32x4;
typedef __attribute__((ext_vector_type(2))) float f32x2;

__device__ __forceinline__ unsigned short f2b(float f) {
    unsigned int u = __builtin_bit_cast(unsigned int, f);
    u += 0x7fffu + ((u >> 16) & 1u);          // RNE
    return (unsigned short)(u >> 16);
}
__device__ __forceinline__ float b2f(unsigned short h) {
    unsigned int u = ((unsigned int)h) << 16;
    return __builtin_bit_cast(float, u);
}

// ---------------- f32 -> bf16 conversion (vectorized, n multiple of 4) ----------------
__global__ void f2b_kernel(const float* __restrict__ in, unsigned short* __restrict__ out, int n4) {
    int i = blockIdx.x * 256 + threadIdx.x;
    if (i < n4) {
        f32x4 v = *(const f32x4*)(in + (size_t)i * 4);
        unsigned short o[4];
#pragma unroll
        for (int j = 0; j < 4; ++j) o[j] = f2b(v[j]);
        *(unsigned long long*)(out + (size_t)i * 4) = *(unsigned long long*)o;
    }
}

// ---------------- RMSNorm: one block per row, writes bf16 ----------------
__global__ void rmsnorm_kernel(const float* __restrict__ x, const float* __restrict__ w,
                               unsigned short* __restrict__ xnb) {
    int row = blockIdx.x;
    const float* xr = x + (size_t)row * DIMX;
    unsigned short* outr = xnb + (size_t)row * DIMX;
    int t = threadIdx.x;
    float v[4];
    float ss = 0.f;
#pragma unroll
    for (int i = 0; i < 4; ++i) { v[i] = xr[t + i * 256]; ss += v[i] * v[i]; }
#pragma unroll
    for (int off = 32; off > 0; off >>= 1) ss += __shfl_down(ss, off);
    __shared__ float red[4];
    if ((t & 63) == 0) red[t >> 6] = ss;
    __syncthreads();
    float tot = red[0] + red[1] + red[2] + red[3];
    float scale = rsqrtf(tot * (1.f / DIMX) + EPSR);
#pragma unroll
    for (int i = 0; i < 4; ++i) outr[t + i * 256] = f2b(v[i] * scale * w[t + i * 256]);
}

// ---------------- bf16 MFMA GEMM: C[M,N] = A[M,K] * B[N,K]^T ----------------
// A, B bf16 row-major (B stored [N,K]).  128x128 tile, BK=32, 4 waves (2x2 of 64x64).
// EPI: 0 none, 1 softplus(acc+bias[n]), 2 acc+res.  WB: also write bf16 copy.
// PERM: permute f32 store cols >=64 into interleaved B/C layout (x_proj).
template <int EPI, int WB, int PERM>
__global__ __launch_bounds__(256) void gemm_mfma(
    const unsigned short* __restrict__ A, const unsigned short* __restrict__ B,
    float* __restrict__ C, unsigned short* __restrict__ Cb,
    int M, int N, int K, int lda, int ldb, int ldc,
    const float* __restrict__ bias, const float* __restrict__ res) {
    __shared__ unsigned short As[128 * 40];   // row stride 40 (pad 8) -> <=2-way bank conflict
    __shared__ unsigned short Bs[128 * 40];
    const int tid = threadIdx.x;
    const int m0 = blockIdx.y * 128, n0 = blockIdx.x * 128;
    const int lane = tid & 63, wave = tid >> 6;
    const int wr = (wave >> 1) * 64, wc = (wave & 1) * 64;
    const int fr = lane & 15, fk = (lane >> 4) * 8;   // fragment row / k-base
    f32x4 acc[4][4] = {};
    for (int k0 = 0; k0 < K; k0 += 32) {
#pragma unroll
        for (int i = 0; i < 2; ++i) {                 // stage A: 512 chunks of 8 bf16
            int c = tid + i * 256;
            int r = c >> 2, c8 = (c & 3) * 8;
            i32x4 v = *(const i32x4*)(A + (size_t)(m0 + r) * lda + k0 + c8);
            *(i32x4*)&As[r * 40 + c8] = v;
        }
#pragma unroll
        for (int i = 0; i < 2; ++i) {                 // stage B with N-guard
            int c = tid + i * 256;
            int r = c >> 2, c8 = (c & 3) * 8;
            i32x4 v = {0, 0, 0, 0};
            if (n0 + r < N) v = *(const i32x4*)(B + (size_t)(n0 + r) * ldb + k0 + c8);
            *(i32x4*)&Bs[r * 40 + c8] = v;
        }
        __syncthreads();
        bf16x8 af[4], bfr[4];
#pragma unroll
        for (int i = 0; i < 4; ++i) af[i]  = *(const bf16x8*)&As[(wr + i * 16 + fr) * 40 + fk];
#pragma unroll
        for (int j = 0; j < 4; ++j) bfr[j] = *(const bf16x8*)&Bs[(wc + j * 16 + fr) * 40 + fk];
#pragma unroll
        for (int i = 0; i < 4; ++i)
#pragma unroll
            for (int j = 0; j < 4; ++j)
                acc[i][j] = __builtin_amdgcn_mfma_f32_16x16x32_bf16(af[i], bfr[j], acc[i][j], 0, 0, 0);
        __syncthreads();
    }
    const int er = (lane >> 4) * 4;
#pragma unroll
    for (int i = 0; i < 4; ++i)
#pragma unroll
        for (int j = 0; j < 4; ++j)
#pragma unroll
            for (int r = 0; r < 4; ++r) {
                int row = m0 + wr + i * 16 + er + r;
                int col = n0 + wc + j * 16 + fr;
                if (col < N) {
                    float v = acc[i][j][r];
                    if (EPI == 1) {
                        v += bias[col];
                        v = fmaxf(v, 0.f) + log1pf(expf(-fabsf(v)));
                    } else if (EPI == 2) {
                        v += res[(size_t)row * ldc + col];
                    }
                    int scol = col;
                    if (PERM && col >= 64) scol = (col < 80) ? (64 + 2 * (col - 64)) : (65 + 2 * (col - 80));
                    C[(size_t)row * ldc + scol] = v;
                    if (WB) Cb[(size_t)row * ldc + col] = f2b(v);
                }
            }
}

// ---------------- Depthwise causal conv (d_conv=4) + SiLU -> bf16 ----------------
__global__ void conv_silu_kernel(const float* __restrict__ xz, const float* __restrict__ cw,
                                 const float* __restrict__ cb, unsigned short* __restrict__ ub) {
    int idx = blockIdx.x * blockDim.x + threadIdx.x;
    if (idx >= B_SZ * L_SEQ * D_INNER) return;
    int d = idx & (D_INNER - 1);
    int bl = idx >> 11;
    int l = bl & (L_SEQ - 1);
    float accv = cb[d];
#pragma unroll
    for (int j = 0; j < 4; ++j) {
        int lp = l - 3 + j;
        if (lp >= 0)
            accv = fmaf(cw[d * 4 + j], xz[(size_t)(bl - l + lp) * (2 * D_INNER) + d], accv);
    }
    ub[idx] = f2b(accv / (1.f + expf(-accv)));
}

// ---------------- Sequential selective scan, lane-per-(channel,state) ----------------
// 16-step prefetch window (4 named 4-step buffers), 3 loads/step.
// B/C come interleaved from x_proj epilogue: float2 at xdbl[tok*96 + 64 + 2s].
struct PfT { float d[4]; float u[4]; f32x2 bc[4]; };

__device__ __forceinline__ void pf_load(PfT& P, const float* dp, const unsigned short* up,
                                        const f32x2* xp, int off) {
#pragma unroll
    for (int q = 0; q < 4; ++q) {
        P.d[q] = dp[(size_t)(off + q) * D_INNER];
        P.u[q] = b2f(up[(size_t)(off + q) * D_INNER]);
        P.bc[q] = xp[(size_t)(off + q) * 48];
    }
}
__device__ __forceinline__ void pf_proc(const PfT& P, float& h, float A, int s,
                                        float* yp, int off) {
#pragma unroll
    for (int q = 0; q < 4; ++q) {
        h = __expf(P.d[q] * A) * h + P.d[q] * P.u[q] * P.bc[q].x;
        float y = h * P.bc[q].y;
        y += __shfl_xor(y, 1);
        y += __shfl_xor(y, 2);
        y += __shfl_xor(y, 4);
        y += __shfl_xor(y, 8);
        if (s == 0) yp[(size_t)(off + q) * D_INNER] = y;
    }
}

__global__ __launch_bounds__(256) void scan_kernel(const float* __restrict__ xdbl,
                                                   float* __restrict__ delta,
                                                   const unsigned short* __restrict__ ub,
                                                   const float* __restrict__ A_log) {
    const int lane = threadIdx.x & 63;
    const int s = lane & 15;
    const int wid = (blockIdx.x << 2) + (threadIdx.x >> 6);
    const int gchan = (wid << 2) + (lane >> 4);
    const int b = gchan >> 11;
    const int d = gchan & (D_INNER - 1);
    const float A = -__expf(A_log[d * D_STATE + s]);
    const size_t tok0 = (size_t)b * L_SEQ;
    const float* dp = delta + tok0 * D_INNER + d;
    const unsigned short* up = ub + tok0 * D_INNER + d;
    const f32x2* xp = (const f32x2*)(xdbl + tok0 * 96 + DT_RANK) + s;
    float* yp = delta + tok0 * D_INNER + d;
    float h = 0.f;

    PfT p0, p1, p2, p3;
    pf_load(p0, dp, up, xp, 0);
    pf_load(p1, dp, up, xp, 4);
    pf_load(p2, dp, up, xp, 8);
    pf_load(p3, dp, up, xp, 12);
    dp += 16 * D_INNER; up += 16 * D_INNER; xp += 16 * 48;
    for (int big = 0; big < 63; ++big) {
        pf_proc(p0, h, A, s, yp, 0);  pf_load(p0, dp, up, xp, 0);
        pf_proc(p1, h, A, s, yp, 4);  pf_load(p1, dp, up, xp, 4);
        pf_proc(p2, h, A, s, yp, 8);  pf_load(p2, dp, up, xp, 8);
        pf_proc(p3, h, A, s, yp, 12); pf_load(p3, dp, up, xp, 12);
        dp += 16 * D_INNER; up += 16 * D_INNER; xp += 16 * 48; yp += 16 * D_INNER;
    }
    pf_proc(p0, h, A, s, yp, 0);
    pf_proc(p1, h, A, s, yp, 4);
    pf_proc(p2, h, A, s, yp, 8);
    pf_proc(p3, h, A, s, yp, 12);
}

// ---------------- y_b = bf16((ys + u*D) * silu(z)) ----------------
__global__ void gate_kernel(const float* __restrict__ ys, const unsigned short* __restrict__ ub,
                            const float* __restrict__ xz, const float* __restrict__ Dp,
                            unsigned short* __restrict__ yb) {
    int idx = blockIdx.x * blockDim.x + threadIdx.x;
    if (idx >= B_SZ * L_SEQ * D_INNER) return;
    int d = idx & (D_INNER - 1);
    int bl = idx >> 11;
    float z = xz[(size_t)bl * (2 * D_INNER) + D_INNER + d];
    float yy = fmaf(b2f(ub[idx]), Dp[d], ys[idx]);
    yb[idx] = f2b(yy * (z / (1.f + expf(-z))));
}

extern "C" void kernel_launch(void* const* d_in, const int* in_sizes, int n_in,
                              void* d_out, int out_size, void* d_ws, size_t ws_size,
                              hipStream_t stream) {
    const float* x          = (const float*)d_in[0];
    const float* norm_w     = (const float*)d_in[1];
    const float* in_proj_w  = (const float*)d_in[2];
    const float* conv_w     = (const float*)d_in[3];
    const float* conv_b     = (const float*)d_in[4];
    const float* x_proj_w   = (const float*)d_in[5];
    const float* dt_proj_w  = (const float*)d_in[6];
    const float* dt_proj_b  = (const float*)d_in[7];
    const float* A_log      = (const float*)d_in[8];
    const float* D_param    = (const float*)d_in[9];
    const float* out_proj_w = (const float*)d_in[10];
    float* out = (float*)d_out;

    char* p = (char*)d_ws;
    float* xz    = (float*)p;            p += (size_t)NTOK * 2 * D_INNER * 4;   // 33.5 MB
    float* xdbl  = (float*)p;            p += (size_t)NTOK * 96 * 4;            // 0.79 MB
    float* delta = (float*)p;            p += (size_t)NTOK * D_INNER * 4;       // 16.8 MB
    unsigned short* xn_b   = (unsigned short*)p; p += (size_t)NTOK * DIMX * 2;      // 4.2 MB
    unsigned short* u_b    = (unsigned short*)p; p += (size_t)NTOK * D_INNER * 2;   // 8.4 MB
    unsigned short* xdbl_b = (unsigned short*)p; p += (size_t)NTOK * 96 * 2;        // 0.39 MB
    unsigned short* y_b    = (unsigned short*)p; p += (size_t)NTOK * D_INNER * 2;   // 8.4 MB
    unsigned short* w_in_b  = (unsigned short*)p; p += (size_t)2 * D_INNER * DIMX * 2;
    unsigned short* w_x_b   = (unsigned short*)p; p += (size_t)96 * D_INNER * 2;
    unsigned short* w_dt_b  = (unsigned short*)p; p += (size_t)D_INNER * DT_RANK * 2;
    unsigned short* w_out_b = (unsigned short*)p; p += (size_t)DIMX * D_INNER * 2;

    // 0. weight conversions f32 -> bf16
    f2b_kernel<<<(2 * D_INNER * DIMX / 4 + 255) / 256, 256, 0, stream>>>(in_proj_w, w_in_b, 2 * D_INNER * DIMX / 4);
    f2b_kernel<<<(96 * D_INNER / 4 + 255) / 256, 256, 0, stream>>>(x_proj_w, w_x_b, 96 * D_INNER / 4);
    f2b_kernel<<<(D_INNER * DT_RANK / 4 + 255) / 256, 256, 0, stream>>>(dt_proj_w, w_dt_b, D_INNER * DT_RANK / 4);
    f2b_kernel<<<(DIMX * D_INNER / 4 + 255) / 256, 256, 0, stream>>>(out_proj_w, w_out_b, DIMX * D_INNER / 4);

    // 1. RMSNorm -> bf16
    rmsnorm_kernel<<<NTOK, 256, 0, stream>>>(x, norm_w, xn_b);
    // 2. in_proj: xz[2048,4096] f32
    gemm_mfma<0, 0, 0><<<dim3(32, 16), 256, 0, stream>>>(xn_b, w_in_b, xz, nullptr,
        NTOK, 2 * D_INNER, DIMX, DIMX, DIMX, 2 * D_INNER, nullptr, nullptr);
    // 3. conv + SiLU -> u bf16
    conv_silu_kernel<<<(B_SZ * L_SEQ * D_INNER) / 256, 256, 0, stream>>>(xz, conv_w, conv_b, u_b);
    // 4. x_proj: xdbl f32 (B/C interleaved for scan) + bf16 copy (dt for dt_proj)
    gemm_mfma<0, 1, 1><<<dim3(1, 16), 256, 0, stream>>>(u_b, w_x_b, xdbl, xdbl_b,
        NTOK, DT_RANK + 2 * D_STATE, D_INNER, D_INNER, D_INNER, 96, nullptr, nullptr);
    // 5. dt_proj + softplus -> delta f32
    gemm_mfma<1, 0, 0><<<dim3(16, 16), 256, 0, stream>>>(xdbl_b, w_dt_b, delta, nullptr,
        NTOK, D_INNER, DT_RANK, 96, DT_RANK, D_INNER, dt_proj_b, nullptr);
    // 6. selective scan (ys over delta)
    scan_kernel<<<256, 256, 0, stream>>>(xdbl, delta, u_b, A_log);
    // 7. gate -> y bf16
    gate_kernel<<<(B_SZ * L_SEQ * D_INNER) / 256, 256, 0, stream>>>(delta, u_b, xz, D_param, y_b);
    // 8. out_proj + residual -> out f32
    gemm_mfma<2, 0, 0><<<dim3(8, 16), 256, 0, stream>>>(y_b, w_out_b, out, nullptr,
        NTOK, DIMX, D_INNER, D_INNER, D_INNER, DIMX, nullptr, x);
}

// Round 4
// 366.937 us; speedup vs baseline: 6.1271x; 1.1979x over previous
//
#include <hip/hip_runtime.h>
#include <math.h>

#define DIMX 1024
#define D_STATE 16
#define D_INNER 2048
#define DT_RANK 64
#define B_SZ 2
#define L_SEQ 1024
#define NTOK (B_SZ * L_SEQ)
#define EPSR 1e-5f
#define NC 16          // chunks over sequence
#define LC 64          // steps per chunk
#define NCH (B_SZ * D_INNER)            // 4096 channels
#define NLANE (NCH * D_STATE)           // 65536 (chan,state) pairs

typedef __attribute__((ext_vector_type(8))) short bf16x8;
typedef __attribute__((ext_vector_type(4))) int   i32x4;
typedef __attribute__((ext_vector_type(4))) float f32x4;
typedef __attribute__((ext_vector_type(2))) float f32x2;

__device__ __forceinline__ unsigned short f2b(float f) {
    unsigned int u = __builtin_bit_cast(unsigned int, f);
    u += 0x7fffu + ((u >> 16) & 1u);          // RNE
    return (unsigned short)(u >> 16);
}
__device__ __forceinline__ float b2f(unsigned short h) {
    unsigned int u = ((unsigned int)h) << 16;
    return __builtin_bit_cast(float, u);
}

// ---------------- f32 -> bf16 conversion (vectorized, n multiple of 4) ----------------
__global__ void f2b_kernel(const float* __restrict__ in, unsigned short* __restrict__ out, int n4) {
    int i = blockIdx.x * 256 + threadIdx.x;
    if (i < n4) {
        f32x4 v = *(const f32x4*)(in + (size_t)i * 4);
        unsigned short o[4];
#pragma unroll
        for (int j = 0; j < 4; ++j) o[j] = f2b(v[j]);
        *(unsigned long long*)(out + (size_t)i * 4) = *(unsigned long long*)o;
    }
}

// ---------------- RMSNorm: one block per row, writes bf16 ----------------
__global__ void rmsnorm_kernel(const float* __restrict__ x, const float* __restrict__ w,
                               unsigned short* __restrict__ xnb) {
    int row = blockIdx.x;
    const float* xr = x + (size_t)row * DIMX;
    unsigned short* outr = xnb + (size_t)row * DIMX;
    int t = threadIdx.x;
    float v[4];
    float ss = 0.f;
#pragma unroll
    for (int i = 0; i < 4; ++i) { v[i] = xr[t + i * 256]; ss += v[i] * v[i]; }
#pragma unroll
    for (int off = 32; off > 0; off >>= 1) ss += __shfl_down(ss, off);
    __shared__ float red[4];
    if ((t & 63) == 0) red[t >> 6] = ss;
    __syncthreads();
    float tot = red[0] + red[1] + red[2] + red[3];
    float scale = rsqrtf(tot * (1.f / DIMX) + EPSR);
#pragma unroll
    for (int i = 0; i < 4; ++i) outr[t + i * 256] = f2b(v[i] * scale * w[t + i * 256]);
}

// ---------------- bf16 MFMA GEMM: C[M,N] = A[M,K] * B[N,K]^T ----------------
template <int EPI, int WB, int PERM>
__global__ __launch_bounds__(256) void gemm_mfma(
    const unsigned short* __restrict__ A, const unsigned short* __restrict__ B,
    float* __restrict__ C, unsigned short* __restrict__ Cb,
    int M, int N, int K, int lda, int ldb, int ldc,
    const float* __restrict__ bias, const float* __restrict__ res) {
    __shared__ unsigned short As[128 * 40];
    __shared__ unsigned short Bs[128 * 40];
    const int tid = threadIdx.x;
    const int m0 = blockIdx.y * 128, n0 = blockIdx.x * 128;
    const int lane = tid & 63, wave = tid >> 6;
    const int wr = (wave >> 1) * 64, wc = (wave & 1) * 64;
    const int fr = lane & 15, fk = (lane >> 4) * 8;
    f32x4 acc[4][4] = {};
    for (int k0 = 0; k0 < K; k0 += 32) {
#pragma unroll
        for (int i = 0; i < 2; ++i) {
            int c = tid + i * 256;
            int r = c >> 2, c8 = (c & 3) * 8;
            i32x4 v = *(const i32x4*)(A + (size_t)(m0 + r) * lda + k0 + c8);
            *(i32x4*)&As[r * 40 + c8] = v;
        }
#pragma unroll
        for (int i = 0; i < 2; ++i) {
            int c = tid + i * 256;
            int r = c >> 2, c8 = (c & 3) * 8;
            i32x4 v = {0, 0, 0, 0};
            if (n0 + r < N) v = *(const i32x4*)(B + (size_t)(n0 + r) * ldb + k0 + c8);
            *(i32x4*)&Bs[r * 40 + c8] = v;
        }
        __syncthreads();
        bf16x8 af[4], bfr[4];
#pragma unroll
        for (int i = 0; i < 4; ++i) af[i]  = *(const bf16x8*)&As[(wr + i * 16 + fr) * 40 + fk];
#pragma unroll
        for (int j = 0; j < 4; ++j) bfr[j] = *(const bf16x8*)&Bs[(wc + j * 16 + fr) * 40 + fk];
#pragma unroll
        for (int i = 0; i < 4; ++i)
#pragma unroll
            for (int j = 0; j < 4; ++j)
                acc[i][j] = __builtin_amdgcn_mfma_f32_16x16x32_bf16(af[i], bfr[j], acc[i][j], 0, 0, 0);
        __syncthreads();
    }
    const int er = (lane >> 4) * 4;
#pragma unroll
    for (int i = 0; i < 4; ++i)
#pragma unroll
        for (int j = 0; j < 4; ++j)
#pragma unroll
            for (int r = 0; r < 4; ++r) {
                int row = m0 + wr + i * 16 + er + r;
                int col = n0 + wc + j * 16 + fr;
                if (col < N) {
                    float v = acc[i][j][r];
                    if (EPI == 1) {
                        v += bias[col];
                        v = fmaxf(v, 0.f) + log1pf(expf(-fabsf(v)));
                    } else if (EPI == 2) {
                        v += res[(size_t)row * ldc + col];
                    }
                    int scol = col;
                    if (PERM && col >= 64) scol = (col < 80) ? (64 + 2 * (col - 64)) : (65 + 2 * (col - 80));
                    C[(size_t)row * ldc + scol] = v;
                    if (WB) Cb[(size_t)row * ldc + col] = f2b(v);
                }
            }
}

// ---------------- Depthwise causal conv (d_conv=4) + SiLU -> bf16 ----------------
__global__ void conv_silu_kernel(const float* __restrict__ xz, const float* __restrict__ cw,
                                 const float* __restrict__ cb, unsigned short* __restrict__ ub) {
    int idx = blockIdx.x * blockDim.x + threadIdx.x;
    if (idx >= B_SZ * L_SEQ * D_INNER) return;
    int d = idx & (D_INNER - 1);
    int bl = idx >> 11;
    int l = bl & (L_SEQ - 1);
    float accv = cb[d];
#pragma unroll
    for (int j = 0; j < 4; ++j) {
        int lp = l - 3 + j;
        if (lp >= 0)
            accv = fmaf(cw[d * 4 + j], xz[(size_t)(bl - l + lp) * (2 * D_INNER) + d], accv);
    }
    ub[idx] = f2b(accv / (1.f + expf(-accv)));
}

// ================= Chunked selective scan =================
// lane mapping (pass1/pass3): wave = 4 channels x 16 states; block = 16 channels.
// grid = 256 channel-groups x 16 chunks.

struct Pf1 { float d[4]; float u[4]; f32x2 bc[4]; };

__device__ __forceinline__ void p1_load(Pf1& P, const float* dp, const unsigned short* up,
                                        const f32x2* xp, int off) {
#pragma unroll
    for (int q = 0; q < 4; ++q) {
        P.d[q] = dp[(size_t)(off + q) * D_INNER];
        P.u[q] = b2f(up[(size_t)(off + q) * D_INNER]);
        P.bc[q] = xp[(size_t)(off + q) * 48];
    }
}
__device__ __forceinline__ void p1_proc(const Pf1& P, float& h, float& Pr, float A) {
#pragma unroll
    for (int q = 0; q < 4; ++q) {
        float e = __expf(P.d[q] * A);
        h = e * h + P.d[q] * P.u[q] * P.bc[q].x;
        Pr *= e;
    }
}

// Pass 1: per-chunk local scan -> hl (chunk-final h), Pc (chunk decay product)
__global__ __launch_bounds__(256) void scan_pass1(
    const float* __restrict__ xdbl, const float* __restrict__ delta,
    const unsigned short* __restrict__ ub, const float* __restrict__ A_log,
    float* __restrict__ hl, float* __restrict__ Pc) {
    const int tid = threadIdx.x, lane = tid & 63;
    const int s = lane & 15;
    const int chunk = blockIdx.x & (NC - 1);
    const int grp = blockIdx.x >> 4;
    const int gchan = grp * 16 + (tid >> 6) * 4 + (lane >> 4);
    const int b = gchan >> 11, d = gchan & (D_INNER - 1);
    const float A = -__expf(A_log[d * D_STATE + s]);
    const size_t tok0 = (size_t)b * L_SEQ + chunk * LC;
    const float* dp = delta + tok0 * D_INNER + d;
    const unsigned short* up = ub + tok0 * D_INNER + d;
    const f32x2* xp = (const f32x2*)(xdbl + tok0 * 96 + DT_RANK) + s;
    float h = 0.f, Pr = 1.f;
    Pf1 pa, pb;
    p1_load(pa, dp, up, xp, 0);
    p1_load(pb, dp, up, xp, 4);
#pragma unroll 1
    for (int t = 0; t < 7; ++t) {
        p1_proc(pa, h, Pr, A);
        p1_load(pa, dp, up, xp, (2 * t + 2) * 4);
        p1_proc(pb, h, Pr, A);
        p1_load(pb, dp, up, xp, (2 * t + 3) * 4);
    }
    p1_proc(pa, h, Pr, A);
    p1_proc(pb, h, Pr, A);
    int o = chunk * NLANE + gchan * D_STATE + s;
    hl[o] = h;
    Pc[o] = Pr;
}

// Pass 2: combine chunk boundaries: hi[c] = H_{c-1}
__global__ __launch_bounds__(256) void scan_pass2(const float* __restrict__ hl,
                                                  const float* __restrict__ Pc,
                                                  float* __restrict__ hi) {
    int gid = blockIdx.x * 256 + threadIdx.x;   // 0..65535
    float h = 0.f;
    hi[gid] = 0.f;
#pragma unroll
    for (int c = 1; c < NC; ++c) {
        h = hl[(c - 1) * NLANE + gid] + Pc[(c - 1) * NLANE + gid] * h;
        hi[c * NLANE + gid] = h;
    }
}

// Pass 3: seeded per-chunk scan + y + fused gate -> y_b (bf16)
struct Pf3 { float d[4]; float u[4]; f32x2 bc[4]; float z[4]; };

__device__ __forceinline__ void p3_load(Pf3& P, const float* dp, const unsigned short* up,
                                        const f32x2* xp, const float* zp, int off) {
#pragma unroll
    for (int q = 0; q < 4; ++q) {
        P.d[q] = dp[(size_t)(off + q) * D_INNER];
        P.u[q] = b2f(up[(size_t)(off + q) * D_INNER]);
        P.bc[q] = xp[(size_t)(off + q) * 48];
        P.z[q] = zp[(size_t)(off + q) * (2 * D_INNER)];
    }
}
__device__ __forceinline__ void p3_proc(const Pf3& P, float& h, float A, int s, float Dpv,
                                        unsigned short* yp, int off) {
#pragma unroll
    for (int q = 0; q < 4; ++q) {
        float e = __expf(P.d[q] * A);
        h = e * h + P.d[q] * P.u[q] * P.bc[q].x;
        float y = h * P.bc[q].y;
        y += __shfl_xor(y, 1);
        y += __shfl_xor(y, 2);
        y += __shfl_xor(y, 4);
        y += __shfl_xor(y, 8);
        if (s == 0) {
            float yy = fmaf(P.u[q], Dpv, y);
            float zz = P.z[q];
            yp[(size_t)(off + q) * D_INNER] = f2b(yy * (zz / (1.f + __expf(-zz))));
        }
    }
}

__global__ __launch_bounds__(256) void scan_pass3(
    const float* __restrict__ xdbl, const float* __restrict__ delta,
    const unsigned short* __restrict__ ub, const float* __restrict__ A_log,
    const float* __restrict__ hi, const float* __restrict__ xz,
    const float* __restrict__ Dp, unsigned short* __restrict__ yb) {
    const int tid = threadIdx.x, lane = tid & 63;
    const int s = lane & 15;
    const int chunk = blockIdx.x & (NC - 1);
    const int grp = blockIdx.x >> 4;
    const int gchan = grp * 16 + (tid >> 6) * 4 + (lane >> 4);
    const int b = gchan >> 11, d = gchan & (D_INNER - 1);
    const float A = -__expf(A_log[d * D_STATE + s]);
    const size_t tok0 = (size_t)b * L_SEQ + chunk * LC;
    const float* dp = delta + tok0 * D_INNER + d;
    const unsigned short* up = ub + tok0 * D_INNER + d;
    const f32x2* xp = (const f32x2*)(xdbl + tok0 * 96 + DT_RANK) + s;
    const float* zp = xz + tok0 * (2 * D_INNER) + D_INNER + d;
    unsigned short* yp = yb + tok0 * D_INNER + d;
    float h = hi[chunk * NLANE + gchan * D_STATE + s];
    const float Dpv = Dp[d];
    Pf3 pa, pb;
    p3_load(pa, dp, up, xp, zp, 0);
    p3_load(pb, dp, up, xp, zp, 4);
#pragma unroll 1
    for (int t = 0; t < 7; ++t) {
        p3_proc(pa, h, A, s, Dpv, yp, 8 * t);
        p3_load(pa, dp, up, xp, zp, (2 * t + 2) * 4);
        p3_proc(pb, h, A, s, Dpv, yp, 8 * t + 4);
        p3_load(pb, dp, up, xp, zp, (2 * t + 3) * 4);
    }
    p3_proc(pa, h, A, s, Dpv, yp, 56);
    p3_proc(pb, h, A, s, Dpv, yp, 60);
}

extern "C" void kernel_launch(void* const* d_in, const int* in_sizes, int n_in,
                              void* d_out, int out_size, void* d_ws, size_t ws_size,
                              hipStream_t stream) {
    const float* x          = (const float*)d_in[0];
    const float* norm_w     = (const float*)d_in[1];
    const float* in_proj_w  = (const float*)d_in[2];
    const float* conv_w     = (const float*)d_in[3];
    const float* conv_b     = (const float*)d_in[4];
    const float* x_proj_w   = (const float*)d_in[5];
    const float* dt_proj_w  = (const float*)d_in[6];
    const float* dt_proj_b  = (const float*)d_in[7];
    const float* A_log      = (const float*)d_in[8];
    const float* D_param    = (const float*)d_in[9];
    const float* out_proj_w = (const float*)d_in[10];
    float* out = (float*)d_out;

    char* p = (char*)d_ws;
    float* xz    = (float*)p;            p += (size_t)NTOK * 2 * D_INNER * 4;   // 33.5 MB
    float* xdbl  = (float*)p;            p += (size_t)NTOK * 96 * 4;            // 0.79 MB
    float* delta = (float*)p;            p += (size_t)NTOK * D_INNER * 4;       // 16.8 MB
    unsigned short* xn_b   = (unsigned short*)p; p += (size_t)NTOK * DIMX * 2;      // 4.19 MB
    unsigned short* u_b    = (unsigned short*)p; p += (size_t)NTOK * D_INNER * 2;   // 8.4 MB
    unsigned short* xdbl_b = (unsigned short*)p; p += (size_t)NTOK * 96 * 2;        // 0.39 MB
    unsigned short* y_b    = (unsigned short*)p; p += (size_t)NTOK * D_INNER * 2;   // 8.4 MB
    unsigned short* w_in_b  = (unsigned short*)p; p += (size_t)2 * D_INNER * DIMX * 2;  // 8.39 MB
    unsigned short* w_x_b   = (unsigned short*)p; p += (size_t)96 * D_INNER * 2;
    unsigned short* w_dt_b  = (unsigned short*)p; p += (size_t)D_INNER * DT_RANK * 2;
    unsigned short* w_out_b = (unsigned short*)p; p += (size_t)DIMX * D_INNER * 2;

    // scan scratch reuses regions dead after in_proj:
    float* hl = (float*)w_in_b;               // 4 MB  (NC*NLANE f32)
    float* Pc = hl + NC * NLANE;              // 4 MB  (fits in w_in_b's 8.39 MB)
    float* hi = (float*)xn_b;                 // 4 MB  (fits in xn_b's 4.19 MB)

    // 0. weight conversions f32 -> bf16
    f2b_kernel<<<(2 * D_INNER * DIMX / 4 + 255) / 256, 256, 0, stream>>>(in_proj_w, w_in_b, 2 * D_INNER * DIMX / 4);
    f2b_kernel<<<(96 * D_INNER / 4 + 255) / 256, 256, 0, stream>>>(x_proj_w, w_x_b, 96 * D_INNER / 4);
    f2b_kernel<<<(D_INNER * DT_RANK / 4 + 255) / 256, 256, 0, stream>>>(dt_proj_w, w_dt_b, D_INNER * DT_RANK / 4);
    f2b_kernel<<<(DIMX * D_INNER / 4 + 255) / 256, 256, 0, stream>>>(out_proj_w, w_out_b, DIMX * D_INNER / 4);

    // 1. RMSNorm -> bf16
    rmsnorm_kernel<<<NTOK, 256, 0, stream>>>(x, norm_w, xn_b);
    // 2. in_proj: xz[2048,4096] f32
    gemm_mfma<0, 0, 0><<<dim3(32, 16), 256, 0, stream>>>(xn_b, w_in_b, xz, nullptr,
        NTOK, 2 * D_INNER, DIMX, DIMX, DIMX, 2 * D_INNER, nullptr, nullptr);
    // 3. conv + SiLU -> u bf16
    conv_silu_kernel<<<(B_SZ * L_SEQ * D_INNER) / 256, 256, 0, stream>>>(xz, conv_w, conv_b, u_b);
    // 4. x_proj: xdbl f32 (B/C interleaved) + bf16 copy (dt)
    gemm_mfma<0, 1, 1><<<dim3(1, 16), 256, 0, stream>>>(u_b, w_x_b, xdbl, xdbl_b,
        NTOK, DT_RANK + 2 * D_STATE, D_INNER, D_INNER, D_INNER, 96, nullptr, nullptr);
    // 5. dt_proj + softplus -> delta f32
    gemm_mfma<1, 0, 0><<<dim3(16, 16), 256, 0, stream>>>(xdbl_b, w_dt_b, delta, nullptr,
        NTOK, D_INNER, DT_RANK, 96, DT_RANK, D_INNER, dt_proj_b, nullptr);
    // 6. chunked selective scan (gate fused into pass 3)
    scan_pass1<<<4096, 256, 0, stream>>>(xdbl, delta, u_b, A_log, hl, Pc);
    scan_pass2<<<NLANE / 256, 256, 0, stream>>>(hl, Pc, hi);
    scan_pass3<<<4096, 256, 0, stream>>>(xdbl, delta, u_b, A_log, hi, xz, D_param, y_b);
    // 7. out_proj + residual -> out f32
    gemm_mfma<2, 0, 0><<<dim3(8, 16), 256, 0, stream>>>(y_b, w_out_b, out, nullptr,
        NTOK, DIMX, D_INNER, D_INNER, D_INNER, DIMX, nullptr, x);
}

// Round 5
// 315.350 us; speedup vs baseline: 7.1294x; 1.1636x over previous
//
#include <hip/hip_runtime.h>
#include <math.h>

#define DIMX 1024
#define D_STATE 16
#define D_INNER 2048
#define DT_RANK 64
#define B_SZ 2
#define L_SEQ 1024
#define NTOK (B_SZ * L_SEQ)
#define EPSR 1e-5f
#define NC 16          // chunks over sequence
#define LC 64          // steps per chunk
#define NCH (B_SZ * D_INNER)            // 4096 channels
#define NLANE (NCH * D_STATE)           // 65536 (chan,state) pairs
#define LOG2E 1.44269504f

typedef __attribute__((ext_vector_type(8))) short bf16x8;
typedef __attribute__((ext_vector_type(4))) int   i32x4;
typedef __attribute__((ext_vector_type(4))) float f32x4;

__device__ __forceinline__ unsigned short f2b(float f) {
    unsigned int u = __builtin_bit_cast(unsigned int, f);
    u += 0x7fffu + ((u >> 16) & 1u);          // RNE
    return (unsigned short)(u >> 16);
}
__device__ __forceinline__ float b2f(unsigned short h) {
    unsigned int u = ((unsigned int)h) << 16;
    return __builtin_bit_cast(float, u);
}

// ---------------- f32 -> bf16 conversion ----------------
__global__ void f2b_kernel(const float* __restrict__ in, unsigned short* __restrict__ out, int n4) {
    int i = blockIdx.x * 256 + threadIdx.x;
    if (i < n4) {
        f32x4 v = *(const f32x4*)(in + (size_t)i * 4);
        unsigned short o[4];
#pragma unroll
        for (int j = 0; j < 4; ++j) o[j] = f2b(v[j]);
        *(unsigned long long*)(out + (size_t)i * 4) = *(unsigned long long*)o;
    }
}

// ---------------- RMSNorm ----------------
__global__ void rmsnorm_kernel(const float* __restrict__ x, const float* __restrict__ w,
                               unsigned short* __restrict__ xnb) {
    int row = blockIdx.x;
    const float* xr = x + (size_t)row * DIMX;
    unsigned short* outr = xnb + (size_t)row * DIMX;
    int t = threadIdx.x;
    float v[4];
    float ss = 0.f;
#pragma unroll
    for (int i = 0; i < 4; ++i) { v[i] = xr[t + i * 256]; ss += v[i] * v[i]; }
#pragma unroll
    for (int off = 32; off > 0; off >>= 1) ss += __shfl_down(ss, off);
    __shared__ float red[4];
    if ((t & 63) == 0) red[t >> 6] = ss;
    __syncthreads();
    float tot = red[0] + red[1] + red[2] + red[3];
    float scale = rsqrtf(tot * (1.f / DIMX) + EPSR);
#pragma unroll
    for (int i = 0; i < 4; ++i) outr[t + i * 256] = f2b(v[i] * scale * w[t + i * 256]);
}

// ---------------- bf16 MFMA GEMM: C[M,N] = A[M,K] * B[N,K]^T ----------------
// AT: A operand stored transposed [K][M] (row length lda) -> staged via LDS transpose.
// EPI 0: plain row-major store (split-K partial via blockIdx.z plane offset)
// EPI 1: softplus(acc + bias[col]) -> TRANSPOSED f32x4 store C[col*ldc + row]
// EPI 2: acc + res[row*ldc+col] row-major
// EPI 3: in_proj split: col<2048 -> C (xi row-major, ldc), col>=2048 -> C2 (z_T transposed f32x4)
template <int EPI, int AT>
__global__ __launch_bounds__(256) void gemm_mfma(
    const unsigned short* __restrict__ A, const unsigned short* __restrict__ B,
    float* __restrict__ C, float* __restrict__ C2,
    int M, int N, int K, int lda, int ldb, int ldc,
    const float* __restrict__ bias, const float* __restrict__ res) {
    __shared__ unsigned short As[128 * 40];
    __shared__ unsigned short Bs[128 * 40];
    const int tid = threadIdx.x;
    const int m0 = blockIdx.y * 128, n0 = blockIdx.x * 128;
    const int lane = tid & 63, wave = tid >> 6;
    const int wr = (wave >> 1) * 64, wc = (wave & 1) * 64;
    const int fr = lane & 15, fk = (lane >> 4) * 8;
    const int kspan = K / gridDim.z;
    const int kb = blockIdx.z * kspan;
    f32x4 acc[4][4] = {};
    for (int k0 = kb; k0 < kb + kspan; k0 += 32) {
        if (AT) {
#pragma unroll
            for (int i = 0; i < 2; ++i) {
                int c = tid + i * 256;
                int kk = c >> 4, tch = c & 15;
                i32x4 v = *(const i32x4*)(A + (size_t)(k0 + kk) * lda + m0 + tch * 8);
                const unsigned short* vs = (const unsigned short*)&v;
#pragma unroll
                for (int t = 0; t < 8; ++t) As[(tch * 8 + t) * 40 + kk] = vs[t];
            }
        } else {
#pragma unroll
            for (int i = 0; i < 2; ++i) {
                int c = tid + i * 256;
                int r = c >> 2, c8 = (c & 3) * 8;
                i32x4 v = *(const i32x4*)(A + (size_t)(m0 + r) * lda + k0 + c8);
                *(i32x4*)&As[r * 40 + c8] = v;
            }
        }
#pragma unroll
        for (int i = 0; i < 2; ++i) {
            int c = tid + i * 256;
            int r = c >> 2, c8 = (c & 3) * 8;
            i32x4 v = {0, 0, 0, 0};
            if (n0 + r < N) v = *(const i32x4*)(B + (size_t)(n0 + r) * ldb + k0 + c8);
            *(i32x4*)&Bs[r * 40 + c8] = v;
        }
        __syncthreads();
        bf16x8 af[4], bfr[4];
#pragma unroll
        for (int i = 0; i < 4; ++i) af[i]  = *(const bf16x8*)&As[(wr + i * 16 + fr) * 40 + fk];
#pragma unroll
        for (int j = 0; j < 4; ++j) bfr[j] = *(const bf16x8*)&Bs[(wc + j * 16 + fr) * 40 + fk];
#pragma unroll
        for (int i = 0; i < 4; ++i)
#pragma unroll
            for (int j = 0; j < 4; ++j)
                acc[i][j] = __builtin_amdgcn_mfma_f32_16x16x32_bf16(af[i], bfr[j], acc[i][j], 0, 0, 0);
        __syncthreads();
    }
    const int er = (lane >> 4) * 4;
    if (EPI == 3) {
        if (n0 < D_INNER) {
#pragma unroll
            for (int i = 0; i < 4; ++i)
#pragma unroll
                for (int j = 0; j < 4; ++j) {
                    int row0 = m0 + wr + i * 16 + er;
                    int col = n0 + wc + j * 16 + fr;
#pragma unroll
                    for (int r = 0; r < 4; ++r)
                        C[(size_t)(row0 + r) * ldc + col] = acc[i][j][r];
                }
        } else {
#pragma unroll
            for (int i = 0; i < 4; ++i)
#pragma unroll
                for (int j = 0; j < 4; ++j) {
                    int row0 = m0 + wr + i * 16 + er;
                    int col = n0 + wc + j * 16 + fr - D_INNER;
                    *(f32x4*)(C2 + (size_t)col * NTOK + row0) = acc[i][j];
                }
        }
    } else if (EPI == 1) {
#pragma unroll
        for (int i = 0; i < 4; ++i)
#pragma unroll
            for (int j = 0; j < 4; ++j) {
                int row0 = m0 + wr + i * 16 + er;
                int col = n0 + wc + j * 16 + fr;
                float bb = bias[col];
                f32x4 v;
#pragma unroll
                for (int r = 0; r < 4; ++r) {
                    float t = acc[i][j][r] + bb;
                    v[r] = fmaxf(t, 0.f) + log1pf(expf(-fabsf(t)));
                }
                *(f32x4*)(C + (size_t)col * ldc + row0) = v;
            }
    } else {
        float* Cs = C + (size_t)blockIdx.z * M * ldc;
#pragma unroll
        for (int i = 0; i < 4; ++i)
#pragma unroll
            for (int j = 0; j < 4; ++j) {
                int col = n0 + wc + j * 16 + fr;
                if (col < N) {
#pragma unroll
                    for (int r = 0; r < 4; ++r) {
                        int row = m0 + wr + i * 16 + er + r;
                        float v = acc[i][j][r];
                        if (EPI == 2) v += res[(size_t)row * ldc + col];
                        Cs[(size_t)row * ldc + col] = v;
                    }
                }
            }
    }
}

// ---------------- Depthwise causal conv + SiLU, writes TRANSPOSED u_T[d][token] ----------------
__global__ __launch_bounds__(256) void conv_silu_t(const float* __restrict__ xi,
                                                   const float* __restrict__ cw,
                                                   const float* __restrict__ cb,
                                                   unsigned short* __restrict__ u_T) {
    __shared__ float xt[67][65];
    const int t0 = blockIdx.x * 64;
    const int d0 = blockIdx.y * 64;
    const int bstart = t0 & ~(L_SEQ - 1);       // batch start token
    const int tid = threadIdx.x;
#pragma unroll
    for (int it = 0; it < 17; ++it) {
        int idx = tid + it * 256;
        if (idx < 67 * 64) {
            int row = idx >> 6, col = idx & 63;
            int tg = t0 - 3 + row;
            xt[row][col] = (tg >= bstart) ? xi[(size_t)tg * D_INNER + d0 + col] : 0.f;
        }
    }
    __syncthreads();
    const int dl = tid & 63, tr = tid >> 6;
    const int d = d0 + dl;
    const float w0 = cw[d * 4 + 0], w1 = cw[d * 4 + 1], w2 = cw[d * 4 + 2], w3 = cw[d * 4 + 3];
    const float bias = cb[d];
    const int r0 = tr * 16;
    float x0 = xt[r0][dl], x1 = xt[r0 + 1][dl], x2 = xt[r0 + 2][dl];
    unsigned short o[16];
#pragma unroll
    for (int i = 0; i < 16; ++i) {
        float x3 = xt[r0 + 3 + i][dl];
        float a = bias + w0 * x0 + w1 * x1 + w2 * x2 + w3 * x3;
        o[i] = f2b(a / (1.f + __expf(-a)));
        x0 = x1; x1 = x2; x2 = x3;
    }
    unsigned short* dst = u_T + (size_t)d * NTOK + t0 + tr * 16;
    *(bf16x8*)(dst)     = *(bf16x8*)(o);
    *(bf16x8*)(dst + 8) = *(bf16x8*)(o + 8);
}

// ---------------- x_proj split-K combine: sum 8 partials, scatter to consumers ----------------
__global__ void xproj_combine(const float* __restrict__ xp, unsigned short* __restrict__ xdbl_b,
                              float* __restrict__ B_T, float* __restrict__ C_T) {
    int row = blockIdx.x;
    int col = threadIdx.x;
    if (col >= 96) return;
    float s = 0.f;
#pragma unroll
    for (int p = 0; p < 8; ++p) s += xp[(size_t)p * NTOK * 96 + (size_t)row * 96 + col];
    if (col < 64) xdbl_b[row * 64 + col] = f2b(s);
    else if (col < 80) B_T[(size_t)(col - 64) * NTOK + row] = s;
    else C_T[(size_t)(col - 80) * NTOK + row] = s;
}

// ================= Chunked selective scan (channel-major layouts) =================
// lane = (c, s): 4 channels x 16 states per wave; per-lane data contiguous over tokens.

struct G1 { f32x4 d0, d1, b0, b1; bf16x8 u; };

__device__ __forceinline__ void g1_load(G1& G, const float* pd, const unsigned short* pu,
                                        const float* pb, int g8) {
    G.d0 = *(const f32x4*)(pd + g8); G.d1 = *(const f32x4*)(pd + g8 + 4);
    G.u  = *(const bf16x8*)(pu + g8);
    G.b0 = *(const f32x4*)(pb + g8); G.b1 = *(const f32x4*)(pb + g8 + 4);
}
__device__ __forceinline__ void g1_proc(const G1& G, float& h, float& Pr, float A2) {
    const unsigned short* us = (const unsigned short*)&G.u;
#pragma unroll
    for (int q = 0; q < 8; ++q) {
        float dq = (q < 4) ? G.d0[q] : G.d1[q - 4];
        float bq = (q < 4) ? G.b0[q] : G.b1[q - 4];
        float e = exp2f(dq * A2);
        h = e * h + dq * b2f(us[q]) * bq;
        Pr *= e;
    }
}

__global__ __launch_bounds__(256) void scan_pass1(
    const float* __restrict__ delta_T, const unsigned short* __restrict__ u_T,
    const float* __restrict__ B_T, const float* __restrict__ A_log,
    float* __restrict__ hl, float* __restrict__ Pc) {
    const int tid = threadIdx.x, lane = tid & 63;
    const int s = lane & 15;
    const int chunk = blockIdx.x & (NC - 1), grp = blockIdx.x >> 4;
    const int gchan = grp * 16 + (tid >> 6) * 4 + (lane >> 4);
    const int b = gchan >> 11, d = gchan & (D_INNER - 1);
    const float A2 = -__expf(A_log[d * D_STATE + s]) * LOG2E;
    const int tb = b * L_SEQ + chunk * LC;
    const float* pd = delta_T + (size_t)d * NTOK + tb;
    const unsigned short* pu = u_T + (size_t)d * NTOK + tb;
    const float* pb = B_T + (size_t)s * NTOK + tb;
    float h = 0.f, Pr = 1.f;
    G1 ga, gb;
    g1_load(ga, pd, pu, pb, 0);
    g1_load(gb, pd, pu, pb, 8);
    g1_proc(ga, h, Pr, A2); g1_load(ga, pd, pu, pb, 16);
    g1_proc(gb, h, Pr, A2); g1_load(gb, pd, pu, pb, 24);
    g1_proc(ga, h, Pr, A2); g1_load(ga, pd, pu, pb, 32);
    g1_proc(gb, h, Pr, A2); g1_load(gb, pd, pu, pb, 40);
    g1_proc(ga, h, Pr, A2); g1_load(ga, pd, pu, pb, 48);
    g1_proc(gb, h, Pr, A2); g1_load(gb, pd, pu, pb, 56);
    g1_proc(ga, h, Pr, A2);
    g1_proc(gb, h, Pr, A2);
    int o = chunk * NLANE + gchan * D_STATE + s;
    hl[o] = h;
    Pc[o] = Pr;
}

__global__ __launch_bounds__(256) void scan_pass2(const float* __restrict__ hl,
                                                  const float* __restrict__ Pc,
                                                  float* __restrict__ hi) {
    int gid = blockIdx.x * 256 + threadIdx.x;
    float h = 0.f;
    hi[gid] = 0.f;
#pragma unroll
    for (int c = 1; c < NC; ++c) {
        h = hl[(c - 1) * NLANE + gid] + Pc[(c - 1) * NLANE + gid] * h;
        hi[c * NLANE + gid] = h;
    }
}

struct G3 { f32x4 d0, d1, b0, b1, c0, c1, z0, z1; bf16x8 u; };

__device__ __forceinline__ void g3_load(G3& G, const float* pd, const unsigned short* pu,
                                        const float* pb, const float* pc, const float* pz, int g8) {
    G.d0 = *(const f32x4*)(pd + g8); G.d1 = *(const f32x4*)(pd + g8 + 4);
    G.u  = *(const bf16x8*)(pu + g8);
    G.b0 = *(const f32x4*)(pb + g8); G.b1 = *(const f32x4*)(pb + g8 + 4);
    G.c0 = *(const f32x4*)(pc + g8); G.c1 = *(const f32x4*)(pc + g8 + 4);
    G.z0 = *(const f32x4*)(pz + g8); G.z1 = *(const f32x4*)(pz + g8 + 4);
}
__device__ __forceinline__ void g3_proc(const G3& G, float& h, float A2, int s, float Dpv,
                                        unsigned short* py, int g8) {
    const unsigned short* us = (const unsigned short*)&G.u;
    float yo[8];
#pragma unroll
    for (int q = 0; q < 8; ++q) {
        float dq = (q < 4) ? G.d0[q] : G.d1[q - 4];
        float bq = (q < 4) ? G.b0[q] : G.b1[q - 4];
        float cq = (q < 4) ? G.c0[q] : G.c1[q - 4];
        float e = exp2f(dq * A2);
        h = e * h + dq * b2f(us[q]) * bq;
        float y = h * cq;
        y += __shfl_xor(y, 1);
        y += __shfl_xor(y, 2);
        y += __shfl_xor(y, 4);
        y += __shfl_xor(y, 8);
        yo[q] = y;
    }
    if (s == 0) {
        unsigned short o[8];
#pragma unroll
        for (int q = 0; q < 8; ++q) {
            float zq = (q < 4) ? G.z0[q] : G.z1[q - 4];
            float yy = fmaf(b2f(us[q]), Dpv, yo[q]);
            o[q] = f2b(yy * (zq / (1.f + __expf(-zq))));
        }
#pragma unroll
        for (int q = 0; q < 8; ++q) py[(size_t)(g8 + q) * D_INNER] = o[q];
    }
}

__global__ __launch_bounds__(256) void scan_pass3(
    const float* __restrict__ delta_T, const unsigned short* __restrict__ u_T,
    const float* __restrict__ B_T, const float* __restrict__ C_T,
    const float* __restrict__ z_T, const float* __restrict__ A_log,
    const float* __restrict__ hi, const float* __restrict__ Dp,
    unsigned short* __restrict__ yb) {
    const int tid = threadIdx.x, lane = tid & 63;
    const int s = lane & 15;
    const int chunk = blockIdx.x & (NC - 1), grp = blockIdx.x >> 4;
    const int gchan = grp * 16 + (tid >> 6) * 4 + (lane >> 4);
    const int b = gchan >> 11, d = gchan & (D_INNER - 1);
    const float A2 = -__expf(A_log[d * D_STATE + s]) * LOG2E;
    const int tb = b * L_SEQ + chunk * LC;
    const float* pd = delta_T + (size_t)d * NTOK + tb;
    const unsigned short* pu = u_T + (size_t)d * NTOK + tb;
    const float* pb = B_T + (size_t)s * NTOK + tb;
    const float* pc = C_T + (size_t)s * NTOK + tb;
    const float* pz = z_T + (size_t)d * NTOK + tb;
    unsigned short* py = yb + (size_t)tb * D_INNER + d;
    float h = hi[chunk * NLANE + gchan * D_STATE + s];
    const float Dpv = Dp[d];
    G3 ga, gb;
    g3_load(ga, pd, pu, pb, pc, pz, 0);
    g3_load(gb, pd, pu, pb, pc, pz, 8);
    g3_proc(ga, h, A2, s, Dpv, py, 0);  g3_load(ga, pd, pu, pb, pc, pz, 16);
    g3_proc(gb, h, A2, s, Dpv, py, 8);  g3_load(gb, pd, pu, pb, pc, pz, 24);
    g3_proc(ga, h, A2, s, Dpv, py, 16); g3_load(ga, pd, pu, pb, pc, pz, 32);
    g3_proc(gb, h, A2, s, Dpv, py, 24); g3_load(gb, pd, pu, pb, pc, pz, 40);
    g3_proc(ga, h, A2, s, Dpv, py, 32); g3_load(ga, pd, pu, pb, pc, pz, 48);
    g3_proc(gb, h, A2, s, Dpv, py, 40); g3_load(gb, pd, pu, pb, pc, pz, 56);
    g3_proc(ga, h, A2, s, Dpv, py, 48);
    g3_proc(gb, h, A2, s, Dpv, py, 56);
}

extern "C" void kernel_launch(void* const* d_in, const int* in_sizes, int n_in,
                              void* d_out, int out_size, void* d_ws, size_t ws_size,
                              hipStream_t stream) {
    const float* x          = (const float*)d_in[0];
    const float* norm_w     = (const float*)d_in[1];
    const float* in_proj_w  = (const float*)d_in[2];
    const float* conv_w     = (const float*)d_in[3];
    const float* conv_b     = (const float*)d_in[4];
    const float* x_proj_w   = (const float*)d_in[5];
    const float* dt_proj_w  = (const float*)d_in[6];
    const float* dt_proj_b  = (const float*)d_in[7];
    const float* A_log      = (const float*)d_in[8];
    const float* D_param    = (const float*)d_in[9];
    const float* out_proj_w = (const float*)d_in[10];
    float* out = (float*)d_out;

    char* p = (char*)d_ws;
    float* xi      = (float*)p;          p += (size_t)NTOK * D_INNER * 4;       // 16.78 MB
    float* z_T     = (float*)p;          p += (size_t)D_INNER * NTOK * 4;       // 16.78 MB
    float* delta_T = (float*)p;          p += (size_t)D_INNER * NTOK * 4;       // 16.78 MB
    unsigned short* u_T    = (unsigned short*)p; p += (size_t)D_INNER * NTOK * 2;   // 8.39 MB
    unsigned short* xdbl_b = (unsigned short*)p; p += (size_t)NTOK * 64 * 2;        // 0.26 MB
    float* B_T     = (float*)p;          p += (size_t)D_STATE * NTOK * 4;       // 0.13 MB
    float* C_T     = (float*)p;          p += (size_t)D_STATE * NTOK * 4;       // 0.13 MB
    unsigned short* y_b    = (unsigned short*)p; p += (size_t)NTOK * D_INNER * 2;   // 8.39 MB
    unsigned short* xn_b   = (unsigned short*)p; p += (size_t)NTOK * DIMX * 2;      // 4.19 MB
    unsigned short* w_in_b  = (unsigned short*)p; p += (size_t)2 * D_INNER * DIMX * 2;  // 8.39 MB
    unsigned short* w_x_b   = (unsigned short*)p; p += (size_t)96 * D_INNER * 2;
    unsigned short* w_dt_b  = (unsigned short*)p; p += (size_t)D_INNER * DT_RANK * 2;
    unsigned short* w_out_b = (unsigned short*)p; p += (size_t)DIMX * D_INNER * 2;

    // overlays (regions dead by the time these are written):
    float* xp_part = (float*)y_b;            // 6.29 MB <= 8.39 (dead before pass3 writes y_b)
    float* hl = (float*)w_in_b;              // 4.19 MB (w_in dead after in_proj)
    float* Pc = hl + NC * NLANE;             // 4.19 MB
    float* hi = (float*)xn_b;                // 4.19 MB (xn dead after in_proj)

    // 0. weight conversions f32 -> bf16
    f2b_kernel<<<(2 * D_INNER * DIMX / 4 + 255) / 256, 256, 0, stream>>>(in_proj_w, w_in_b, 2 * D_INNER * DIMX / 4);
    f2b_kernel<<<(96 * D_INNER / 4 + 255) / 256, 256, 0, stream>>>(x_proj_w, w_x_b, 96 * D_INNER / 4);
    f2b_kernel<<<(D_INNER * DT_RANK / 4 + 255) / 256, 256, 0, stream>>>(dt_proj_w, w_dt_b, D_INNER * DT_RANK / 4);
    f2b_kernel<<<(DIMX * D_INNER / 4 + 255) / 256, 256, 0, stream>>>(out_proj_w, w_out_b, DIMX * D_INNER / 4);

    // 1. RMSNorm -> bf16
    rmsnorm_kernel<<<NTOK, 256, 0, stream>>>(x, norm_w, xn_b);
    // 2. in_proj: xi[token][d] f32 + z_T[d][token] f32
    gemm_mfma<3, 0><<<dim3(32, 16), 256, 0, stream>>>(xn_b, w_in_b, xi, z_T,
        NTOK, 2 * D_INNER, DIMX, DIMX, DIMX, D_INNER, nullptr, nullptr);
    // 3. conv + SiLU -> u_T[d][token] bf16
    conv_silu_t<<<dim3(NTOK / 64, D_INNER / 64), 256, 0, stream>>>(xi, conv_w, conv_b, u_T);
    // 4. x_proj split-K=8 partials (A = u_T transposed-staged)
    gemm_mfma<0, 1><<<dim3(1, 16, 8), 256, 0, stream>>>(u_T, w_x_b, xp_part, nullptr,
        NTOK, 96, D_INNER, NTOK, D_INNER, 96, nullptr, nullptr);
    xproj_combine<<<NTOK, 128, 0, stream>>>(xp_part, xdbl_b, B_T, C_T);
    // 5. dt_proj + softplus -> delta_T[d][token] f32 (transposed epilogue)
    gemm_mfma<1, 0><<<dim3(16, 16), 256, 0, stream>>>(xdbl_b, w_dt_b, delta_T, nullptr,
        NTOK, D_INNER, DT_RANK, 64, DT_RANK, NTOK, dt_proj_b, nullptr);
    // 6. chunked selective scan (gate fused into pass 3)
    scan_pass1<<<4096, 256, 0, stream>>>(delta_T, u_T, B_T, A_log, hl, Pc);
    scan_pass2<<<NLANE / 256, 256, 0, stream>>>(hl, Pc, hi);
    scan_pass3<<<4096, 256, 0, stream>>>(delta_T, u_T, B_T, C_T, z_T, A_log, hi, D_param, y_b);
    // 7. out_proj + residual -> out f32
    gemm_mfma<2, 0><<<dim3(8, 16), 256, 0, stream>>>(y_b, w_out_b, out, nullptr,
        NTOK, DIMX, D_INNER, D_INNER, D_INNER, DIMX, nullptr, x);
}

// Round 6
// 309.434 us; speedup vs baseline: 7.2657x; 1.0191x over previous
//
#include <hip/hip_runtime.h>
#include <math.h>

#define DIMX 1024
#define D_STATE 16
#define D_INNER 2048
#define DT_RANK 64
#define B_SZ 2
#define L_SEQ 1024
#define NTOK (B_SZ * L_SEQ)
#define EPSR 1e-5f
#define NC 16          // chunks over sequence
#define LC 64          // steps per chunk
#define NCH (B_SZ * D_INNER)            // 4096 channels
#define NLANE (NCH * D_STATE)           // 65536 (chan,state) pairs
#define LOG2E 1.44269504f

typedef __attribute__((ext_vector_type(8))) short bf16x8;
typedef __attribute__((ext_vector_type(4))) int   i32x4;
typedef __attribute__((ext_vector_type(4))) float f32x4;
typedef __attribute__((ext_vector_type(4))) unsigned short u16x4;

__device__ __forceinline__ unsigned short f2b(float f) {
    unsigned int u = __builtin_bit_cast(unsigned int, f);
    u += 0x7fffu + ((u >> 16) & 1u);          // RNE
    return (unsigned short)(u >> 16);
}
__device__ __forceinline__ float b2f(unsigned short h) {
    unsigned int u = ((unsigned int)h) << 16;
    return __builtin_bit_cast(float, u);
}

// ---------------- f32 -> bf16 conversion ----------------
__global__ void f2b_kernel(const float* __restrict__ in, unsigned short* __restrict__ out, int n4) {
    int i = blockIdx.x * 256 + threadIdx.x;
    if (i < n4) {
        f32x4 v = *(const f32x4*)(in + (size_t)i * 4);
        unsigned short o[4];
#pragma unroll
        for (int j = 0; j < 4; ++j) o[j] = f2b(v[j]);
        *(unsigned long long*)(out + (size_t)i * 4) = *(unsigned long long*)o;
    }
}

// ---------------- RMSNorm ----------------
__global__ void rmsnorm_kernel(const float* __restrict__ x, const float* __restrict__ w,
                               unsigned short* __restrict__ xnb) {
    int row = blockIdx.x;
    const float* xr = x + (size_t)row * DIMX;
    unsigned short* outr = xnb + (size_t)row * DIMX;
    int t = threadIdx.x;
    float v[4];
    float ss = 0.f;
#pragma unroll
    for (int i = 0; i < 4; ++i) { v[i] = xr[t + i * 256]; ss += v[i] * v[i]; }
#pragma unroll
    for (int off = 32; off > 0; off >>= 1) ss += __shfl_down(ss, off);
    __shared__ float red[4];
    if ((t & 63) == 0) red[t >> 6] = ss;
    __syncthreads();
    float tot = red[0] + red[1] + red[2] + red[3];
    float scale = rsqrtf(tot * (1.f / DIMX) + EPSR);
#pragma unroll
    for (int i = 0; i < 4; ++i) outr[t + i * 256] = f2b(v[i] * scale * w[t + i * 256]);
}

// ---------------- bf16 MFMA GEMM: C[M,N] = A[M,K] * B[N,K]^T ----------------
// AT: A operand stored transposed [K][M].
// EPI 0: row-major store (split-K partial via blockIdx.z)
// EPI 1: dt_proj: delta = softplus(acc+bias[col]) -> TRANSPOSED C[col*ldc+row];
//        ALSO du = delta * b2f(u_T[col*NTOK+row]) -> C2 (res param carries u_T!)
// EPI 2: acc + res[row*ldc+col] row-major
// EPI 3: in_proj split: col<2048 -> C (xi row-major), col>=2048 -> C2 (z_T transposed)
template <int EPI, int AT>
__global__ __launch_bounds__(256) void gemm_mfma(
    const unsigned short* __restrict__ A, const unsigned short* __restrict__ B,
    float* __restrict__ C, float* __restrict__ C2,
    int M, int N, int K, int lda, int ldb, int ldc,
    const float* __restrict__ bias, const float* __restrict__ res) {
    __shared__ unsigned short As[128 * 40];
    __shared__ unsigned short Bs[128 * 40];
    const int tid = threadIdx.x;
    const int m0 = blockIdx.y * 128, n0 = blockIdx.x * 128;
    const int lane = tid & 63, wave = tid >> 6;
    const int wr = (wave >> 1) * 64, wc = (wave & 1) * 64;
    const int fr = lane & 15, fk = (lane >> 4) * 8;
    const int kspan = K / gridDim.z;
    const int kb = blockIdx.z * kspan;
    f32x4 acc[4][4] = {};
    for (int k0 = kb; k0 < kb + kspan; k0 += 32) {
        if (AT) {
#pragma unroll
            for (int i = 0; i < 2; ++i) {
                int c = tid + i * 256;
                int kk = c >> 4, tch = c & 15;
                i32x4 v = *(const i32x4*)(A + (size_t)(k0 + kk) * lda + m0 + tch * 8);
                const unsigned short* vs = (const unsigned short*)&v;
#pragma unroll
                for (int t = 0; t < 8; ++t) As[(tch * 8 + t) * 40 + kk] = vs[t];
            }
        } else {
#pragma unroll
            for (int i = 0; i < 2; ++i) {
                int c = tid + i * 256;
                int r = c >> 2, c8 = (c & 3) * 8;
                i32x4 v = *(const i32x4*)(A + (size_t)(m0 + r) * lda + k0 + c8);
                *(i32x4*)&As[r * 40 + c8] = v;
            }
        }
#pragma unroll
        for (int i = 0; i < 2; ++i) {
            int c = tid + i * 256;
            int r = c >> 2, c8 = (c & 3) * 8;
            i32x4 v = {0, 0, 0, 0};
            if (n0 + r < N) v = *(const i32x4*)(B + (size_t)(n0 + r) * ldb + k0 + c8);
            *(i32x4*)&Bs[r * 40 + c8] = v;
        }
        __syncthreads();
        bf16x8 af[4], bfr[4];
#pragma unroll
        for (int i = 0; i < 4; ++i) af[i]  = *(const bf16x8*)&As[(wr + i * 16 + fr) * 40 + fk];
#pragma unroll
        for (int j = 0; j < 4; ++j) bfr[j] = *(const bf16x8*)&Bs[(wc + j * 16 + fr) * 40 + fk];
#pragma unroll
        for (int i = 0; i < 4; ++i)
#pragma unroll
            for (int j = 0; j < 4; ++j)
                acc[i][j] = __builtin_amdgcn_mfma_f32_16x16x32_bf16(af[i], bfr[j], acc[i][j], 0, 0, 0);
        __syncthreads();
    }
    const int er = (lane >> 4) * 4;
    if (EPI == 3) {
        if (n0 < D_INNER) {
#pragma unroll
            for (int i = 0; i < 4; ++i)
#pragma unroll
                for (int j = 0; j < 4; ++j) {
                    int row0 = m0 + wr + i * 16 + er;
                    int col = n0 + wc + j * 16 + fr;
#pragma unroll
                    for (int r = 0; r < 4; ++r)
                        C[(size_t)(row0 + r) * ldc + col] = acc[i][j][r];
                }
        } else {
#pragma unroll
            for (int i = 0; i < 4; ++i)
#pragma unroll
                for (int j = 0; j < 4; ++j) {
                    int row0 = m0 + wr + i * 16 + er;
                    int col = n0 + wc + j * 16 + fr - D_INNER;
                    *(f32x4*)(C2 + (size_t)col * NTOK + row0) = acc[i][j];
                }
        }
    } else if (EPI == 1) {
        const unsigned short* uT = (const unsigned short*)res;   // u_T bf16, [d][token]
#pragma unroll
        for (int i = 0; i < 4; ++i)
#pragma unroll
            for (int j = 0; j < 4; ++j) {
                int row0 = m0 + wr + i * 16 + er;
                int col = n0 + wc + j * 16 + fr;
                float bb = bias[col];
                u16x4 uu = *(const u16x4*)(uT + (size_t)col * NTOK + row0);
                f32x4 v, dv;
#pragma unroll
                for (int r = 0; r < 4; ++r) {
                    float t = acc[i][j][r] + bb;
                    v[r] = fmaxf(t, 0.f) + log1pf(expf(-fabsf(t)));
                    dv[r] = v[r] * b2f(uu[r]);
                }
                *(f32x4*)(C  + (size_t)col * ldc + row0) = v;
                *(f32x4*)(C2 + (size_t)col * ldc + row0) = dv;
            }
    } else {
        float* Cs = C + (size_t)blockIdx.z * M * ldc;
#pragma unroll
        for (int i = 0; i < 4; ++i)
#pragma unroll
            for (int j = 0; j < 4; ++j) {
                int col = n0 + wc + j * 16 + fr;
                if (col < N) {
#pragma unroll
                    for (int r = 0; r < 4; ++r) {
                        int row = m0 + wr + i * 16 + er + r;
                        float v = acc[i][j][r];
                        if (EPI == 2) v += res[(size_t)row * ldc + col];
                        Cs[(size_t)row * ldc + col] = v;
                    }
                }
            }
    }
}

// ---------------- Depthwise causal conv + SiLU, writes TRANSPOSED u_T[d][token] ----------------
__global__ __launch_bounds__(256) void conv_silu_t(const float* __restrict__ xi,
                                                   const float* __restrict__ cw,
                                                   const float* __restrict__ cb,
                                                   unsigned short* __restrict__ u_T) {
    __shared__ float xt[67][65];
    const int t0 = blockIdx.x * 64;
    const int d0 = blockIdx.y * 64;
    const int bstart = t0 & ~(L_SEQ - 1);       // batch start token
    const int tid = threadIdx.x;
#pragma unroll
    for (int it = 0; it < 17; ++it) {
        int idx = tid + it * 256;
        if (idx < 67 * 64) {
            int row = idx >> 6, col = idx & 63;
            int tg = t0 - 3 + row;
            xt[row][col] = (tg >= bstart) ? xi[(size_t)tg * D_INNER + d0 + col] : 0.f;
        }
    }
    __syncthreads();
    const int dl = tid & 63, tr = tid >> 6;
    const int d = d0 + dl;
    const float w0 = cw[d * 4 + 0], w1 = cw[d * 4 + 1], w2 = cw[d * 4 + 2], w3 = cw[d * 4 + 3];
    const float bias = cb[d];
    const int r0 = tr * 16;
    float x0 = xt[r0][dl], x1 = xt[r0 + 1][dl], x2 = xt[r0 + 2][dl];
    unsigned short o[16];
#pragma unroll
    for (int i = 0; i < 16; ++i) {
        float x3 = xt[r0 + 3 + i][dl];
        float a = bias + w0 * x0 + w1 * x1 + w2 * x2 + w3 * x3;
        o[i] = f2b(a / (1.f + __expf(-a)));
        x0 = x1; x1 = x2; x2 = x3;
    }
    unsigned short* dst = u_T + (size_t)d * NTOK + t0 + tr * 16;
    *(bf16x8*)(dst)     = *(bf16x8*)(o);
    *(bf16x8*)(dst + 8) = *(bf16x8*)(o + 8);
}

// ---------------- x_proj split-K combine ----------------
__global__ void xproj_combine(const float* __restrict__ xp, unsigned short* __restrict__ xdbl_b,
                              float* __restrict__ B_T, float* __restrict__ C_T) {
    int row = blockIdx.x;
    int col = threadIdx.x;
    if (col >= 96) return;
    float s = 0.f;
#pragma unroll
    for (int p = 0; p < 8; ++p) s += xp[(size_t)p * NTOK * 96 + (size_t)row * 96 + col];
    if (col < 64) xdbl_b[row * 64 + col] = f2b(s);
    else if (col < 80) B_T[(size_t)(col - 64) * NTOK + row] = s;
    else C_T[(size_t)(col - 80) * NTOK + row] = s;
}

// ================= Chunked selective scan (channel-major, du precomputed) =================

struct G1 { f32x4 d0, d1, e0, e1, b0, b1; };

__device__ __forceinline__ void g1_load(G1& G, const float* pd, const float* pe,
                                        const float* pb, int g8) {
    G.d0 = *(const f32x4*)(pd + g8); G.d1 = *(const f32x4*)(pd + g8 + 4);
    G.e0 = *(const f32x4*)(pe + g8); G.e1 = *(const f32x4*)(pe + g8 + 4);
    G.b0 = *(const f32x4*)(pb + g8); G.b1 = *(const f32x4*)(pb + g8 + 4);
}
__device__ __forceinline__ void g1_proc(const G1& G, float& h, float& Pr, float A2) {
#pragma unroll
    for (int q = 0; q < 8; ++q) {
        float dq = (q < 4) ? G.d0[q] : G.d1[q - 4];
        float eq = (q < 4) ? G.e0[q] : G.e1[q - 4];
        float bq = (q < 4) ? G.b0[q] : G.b1[q - 4];
        float e = exp2f(dq * A2);
        h = e * h + eq * bq;
        Pr *= e;
    }
}

__global__ __launch_bounds__(256) void scan_pass1(
    const float* __restrict__ delta_T, const float* __restrict__ du_T,
    const float* __restrict__ B_T, const float* __restrict__ A_log,
    float* __restrict__ hl, float* __restrict__ Pc) {
    const int tid = threadIdx.x, lane = tid & 63;
    const int s = lane & 15;
    const int chunk = blockIdx.x & (NC - 1), grp = blockIdx.x >> 4;
    const int gchan = grp * 16 + (tid >> 6) * 4 + (lane >> 4);
    const int b = gchan >> 11, d = gchan & (D_INNER - 1);
    const float A2 = -__expf(A_log[d * D_STATE + s]) * LOG2E;
    const int tb = b * L_SEQ + chunk * LC;
    const float* pd = delta_T + (size_t)d * NTOK + tb;
    const float* pe = du_T + (size_t)d * NTOK + tb;
    const float* pb = B_T + (size_t)s * NTOK + tb;
    float h = 0.f, Pr = 1.f;
    G1 ga, gb;
    g1_load(ga, pd, pe, pb, 0);
    g1_load(gb, pd, pe, pb, 8);
    g1_proc(ga, h, Pr, A2); g1_load(ga, pd, pe, pb, 16);
    g1_proc(gb, h, Pr, A2); g1_load(gb, pd, pe, pb, 24);
    g1_proc(ga, h, Pr, A2); g1_load(ga, pd, pe, pb, 32);
    g1_proc(gb, h, Pr, A2); g1_load(gb, pd, pe, pb, 40);
    g1_proc(ga, h, Pr, A2); g1_load(ga, pd, pe, pb, 48);
    g1_proc(gb, h, Pr, A2); g1_load(gb, pd, pe, pb, 56);
    g1_proc(ga, h, Pr, A2);
    g1_proc(gb, h, Pr, A2);
    int o = chunk * NLANE + gchan * D_STATE + s;
    hl[o] = h;
    Pc[o] = Pr;
}

__global__ __launch_bounds__(256) void scan_pass2(const float* __restrict__ hl,
                                                  const float* __restrict__ Pc,
                                                  float* __restrict__ hi) {
    int gid = blockIdx.x * 256 + threadIdx.x;
    float h = 0.f;
    hi[gid] = 0.f;
#pragma unroll
    for (int c = 1; c < NC; ++c) {
        h = hl[(c - 1) * NLANE + gid] + Pc[(c - 1) * NLANE + gid] * h;
        hi[c * NLANE + gid] = h;
    }
}

struct G3 { f32x4 d0, d1, e0, e1, b0, b1, c0, c1; };

__device__ __forceinline__ void g3_load(G3& G, const float* pd, const float* pe,
                                        const float* pb, const float* pc, int g8) {
    G.d0 = *(const f32x4*)(pd + g8); G.d1 = *(const f32x4*)(pd + g8 + 4);
    G.e0 = *(const f32x4*)(pe + g8); G.e1 = *(const f32x4*)(pe + g8 + 4);
    G.b0 = *(const f32x4*)(pb + g8); G.b1 = *(const f32x4*)(pb + g8 + 4);
    G.c0 = *(const f32x4*)(pc + g8); G.c1 = *(const f32x4*)(pc + g8 + 4);
}

// Reduce-scatter over the 16-lane state group: lane s ends holding the full
// 16-state sum for step (s&7) (duplicated on s and s^8). Static reg indices.
__device__ __forceinline__ void g3_proc(const G3& G, float& h, float A2, int s,
                                        float Dpv, const unsigned short* pu,
                                        const float* pz, unsigned short* py, int g8) {
    float y[8];
#pragma unroll
    for (int q = 0; q < 8; ++q) {
        float dq = (q < 4) ? G.d0[q] : G.d1[q - 4];
        float eq = (q < 4) ? G.e0[q] : G.e1[q - 4];
        float bq = (q < 4) ? G.b0[q] : G.b1[q - 4];
        float cq = (q < 4) ? G.c0[q] : G.c1[q - 4];
        float e = exp2f(dq * A2);
        h = e * h + eq * bq;
        y[q] = h * cq;
    }
    const bool b4 = (s & 4) != 0, b2_ = (s & 2) != 0, b1 = (s & 1) != 0;
#pragma unroll
    for (int i = 0; i < 4; ++i) {
        float give = b4 ? y[i] : y[i + 4];
        float keep = b4 ? y[i + 4] : y[i];
        y[i] = keep + __shfl_xor(give, 4);
    }
#pragma unroll
    for (int i = 0; i < 2; ++i) {
        float give = b2_ ? y[i] : y[i + 2];
        float keep = b2_ ? y[i + 2] : y[i];
        y[i] = keep + __shfl_xor(give, 2);
    }
    {
        float give = b1 ? y[0] : y[1];
        float keep = b1 ? y[1] : y[0];
        y[0] = keep + __shfl_xor(give, 1);
    }
    y[0] += __shfl_xor(y[0], 8);
    if (!(s & 8)) {
        int q = s & 7;
        float uu = b2f(pu[g8 + q]);
        float zz = pz[g8 + q];
        float yy = fmaf(uu, Dpv, y[0]);
        py[(size_t)(g8 + q) * D_INNER] = f2b(yy * (zz / (1.f + __expf(-zz))));
    }
}

__global__ __launch_bounds__(256) void scan_pass3(
    const float* __restrict__ delta_T, const float* __restrict__ du_T,
    const unsigned short* __restrict__ u_T,
    const float* __restrict__ B_T, const float* __restrict__ C_T,
    const float* __restrict__ z_T, const float* __restrict__ A_log,
    const float* __restrict__ hi, const float* __restrict__ Dp,
    unsigned short* __restrict__ yb) {
    const int tid = threadIdx.x, lane = tid & 63;
    const int s = lane & 15;
    const int chunk = blockIdx.x & (NC - 1), grp = blockIdx.x >> 4;
    const int gchan = grp * 16 + (tid >> 6) * 4 + (lane >> 4);
    const int b = gchan >> 11, d = gchan & (D_INNER - 1);
    const float A2 = -__expf(A_log[d * D_STATE + s]) * LOG2E;
    const int tb = b * L_SEQ + chunk * LC;
    const float* pd = delta_T + (size_t)d * NTOK + tb;
    const float* pe = du_T + (size_t)d * NTOK + tb;
    const float* pb = B_T + (size_t)s * NTOK + tb;
    const float* pc = C_T + (size_t)s * NTOK + tb;
    const float* pz = z_T + (size_t)d * NTOK + tb;
    const unsigned short* pu = u_T + (size_t)d * NTOK + tb;
    unsigned short* py = yb + (size_t)tb * D_INNER + d;
    float h = hi[chunk * NLANE + gchan * D_STATE + s];
    const float Dpv = Dp[d];
    G3 ga, gb;
    g3_load(ga, pd, pe, pb, pc, 0);
    g3_load(gb, pd, pe, pb, pc, 8);
    g3_proc(ga, h, A2, s, Dpv, pu, pz, py, 0);  g3_load(ga, pd, pe, pb, pc, 16);
    g3_proc(gb, h, A2, s, Dpv, pu, pz, py, 8);  g3_load(gb, pd, pe, pb, pc, 24);
    g3_proc(ga, h, A2, s, Dpv, pu, pz, py, 16); g3_load(ga, pd, pe, pb, pc, 32);
    g3_proc(gb, h, A2, s, Dpv, pu, pz, py, 24); g3_load(gb, pd, pe, pb, pc, 40);
    g3_proc(ga, h, A2, s, Dpv, pu, pz, py, 32); g3_load(ga, pd, pe, pb, pc, 48);
    g3_proc(gb, h, A2, s, Dpv, pu, pz, py, 40); g3_load(gb, pd, pe, pb, pc, 56);
    g3_proc(ga, h, A2, s, Dpv, pu, pz, py, 48);
    g3_proc(gb, h, A2, s, Dpv, pu, pz, py, 56);
}

extern "C" void kernel_launch(void* const* d_in, const int* in_sizes, int n_in,
                              void* d_out, int out_size, void* d_ws, size_t ws_size,
                              hipStream_t stream) {
    const float* x          = (const float*)d_in[0];
    const float* norm_w     = (const float*)d_in[1];
    const float* in_proj_w  = (const float*)d_in[2];
    const float* conv_w     = (const float*)d_in[3];
    const float* conv_b     = (const float*)d_in[4];
    const float* x_proj_w   = (const float*)d_in[5];
    const float* dt_proj_w  = (const float*)d_in[6];
    const float* dt_proj_b  = (const float*)d_in[7];
    const float* A_log      = (const float*)d_in[8];
    const float* D_param    = (const float*)d_in[9];
    const float* out_proj_w = (const float*)d_in[10];
    float* out = (float*)d_out;

    char* p = (char*)d_ws;
    float* xi      = (float*)p;          p += (size_t)NTOK * D_INNER * 4;       // 16.78 MB
    float* z_T     = (float*)p;          p += (size_t)D_INNER * NTOK * 4;       // 16.78 MB
    float* delta_T = (float*)p;          p += (size_t)D_INNER * NTOK * 4;       // 16.78 MB
    unsigned short* u_T    = (unsigned short*)p; p += (size_t)D_INNER * NTOK * 2;   // 8.39 MB
    unsigned short* xdbl_b = (unsigned short*)p; p += (size_t)NTOK * 64 * 2;        // 0.26 MB
    float* B_T     = (float*)p;          p += (size_t)D_STATE * NTOK * 4;       // 0.13 MB
    float* C_T     = (float*)p;          p += (size_t)D_STATE * NTOK * 4;       // 0.13 MB
    unsigned short* y_b    = (unsigned short*)p; p += (size_t)NTOK * D_INNER * 2;   // 8.39 MB
    unsigned short* xn_b   = (unsigned short*)p; p += (size_t)NTOK * DIMX * 2;      // 4.19 MB
    unsigned short* w_in_b  = (unsigned short*)p; p += (size_t)2 * D_INNER * DIMX * 2;  // 8.39 MB
    unsigned short* w_x_b   = (unsigned short*)p; p += (size_t)96 * D_INNER * 2;
    unsigned short* w_dt_b  = (unsigned short*)p; p += (size_t)D_INNER * DT_RANK * 2;
    unsigned short* w_out_b = (unsigned short*)p; p += (size_t)DIMX * D_INNER * 2;

    // overlays (regions dead by the time these are written):
    float* du_T    = xi;                     // 16.78 MB (xi dead after conv_silu_t)
    float* xp_part = (float*)y_b;            // 6.29 MB  (dead before pass3 writes y_b)
    float* hl = (float*)w_in_b;              // 4.19 MB  (w_in dead after in_proj)
    float* Pc = hl + NC * NLANE;             // 4.19 MB
    float* hi = (float*)xn_b;                // 4.19 MB  (xn dead after in_proj)

    // 0. weight conversions f32 -> bf16
    f2b_kernel<<<(2 * D_INNER * DIMX / 4 + 255) / 256, 256, 0, stream>>>(in_proj_w, w_in_b, 2 * D_INNER * DIMX / 4);
    f2b_kernel<<<(96 * D_INNER / 4 + 255) / 256, 256, 0, stream>>>(x_proj_w, w_x_b, 96 * D_INNER / 4);
    f2b_kernel<<<(D_INNER * DT_RANK / 4 + 255) / 256, 256, 0, stream>>>(dt_proj_w, w_dt_b, D_INNER * DT_RANK / 4);
    f2b_kernel<<<(DIMX * D_INNER / 4 + 255) / 256, 256, 0, stream>>>(out_proj_w, w_out_b, DIMX * D_INNER / 4);

    // 1. RMSNorm -> bf16
    rmsnorm_kernel<<<NTOK, 256, 0, stream>>>(x, norm_w, xn_b);
    // 2. in_proj: xi[token][d] f32 + z_T[d][token] f32
    gemm_mfma<3, 0><<<dim3(32, 16), 256, 0, stream>>>(xn_b, w_in_b, xi, z_T,
        NTOK, 2 * D_INNER, DIMX, DIMX, DIMX, D_INNER, nullptr, nullptr);
    // 3. conv + SiLU -> u_T[d][token] bf16
    conv_silu_t<<<dim3(NTOK / 64, D_INNER / 64), 256, 0, stream>>>(xi, conv_w, conv_b, u_T);
    // 4. x_proj split-K=8 partials + combine
    gemm_mfma<0, 1><<<dim3(1, 16, 8), 256, 0, stream>>>(u_T, w_x_b, xp_part, nullptr,
        NTOK, 96, D_INNER, NTOK, D_INNER, 96, nullptr, nullptr);
    xproj_combine<<<NTOK, 128, 0, stream>>>(xp_part, xdbl_b, B_T, C_T);
    // 5. dt_proj + softplus -> delta_T f32 AND du_T = delta*u f32 (u_T via res param)
    gemm_mfma<1, 0><<<dim3(16, 16), 256, 0, stream>>>(xdbl_b, w_dt_b, delta_T, du_T,
        NTOK, D_INNER, DT_RANK, 64, DT_RANK, NTOK, dt_proj_b, (const float*)u_T);
    // 6. chunked selective scan (gate fused into pass 3)
    scan_pass1<<<4096, 256, 0, stream>>>(delta_T, du_T, B_T, A_log, hl, Pc);
    scan_pass2<<<NLANE / 256, 256, 0, stream>>>(hl, Pc, hi);
    scan_pass3<<<4096, 256, 0, stream>>>(delta_T, du_T, u_T, B_T, C_T, z_T, A_log, hi, D_param, y_b);
    // 7. out_proj + residual -> out f32
    gemm_mfma<2, 0><<<dim3(8, 16), 256, 0, stream>>>(y_b, w_out_b, out, nullptr,
        NTOK, DIMX, D_INNER, D_INNER, D_INNER, DIMX, nullptr, x);
}